// Round 3
// baseline (278.670 us; speedup 1.0000x reference)
//
#include <hip/hip_runtime.h>
#include <hip/hip_bf16.h>
#include <stdint.h>

// ---------------------------------------------------------------------------
// CausalSelfAttention: x(4,2048,1024) fp32 -> out fp32
// qkv = x@w_attn+b_attn; flash-attn causal (H=16,hd=64); out = attn@w_proj+b_proj
// R9: gemm256sq — per-wave tile 64x64 -> 128x64 (m201 geometry). R8 was
//   LDS-read-bound: 64x64/wave needs 16KB LDS reads per 524KFLOP -> 1536cyc
//   LDS vs 1024cyc MFMA per CU-tile -> MfmaUtil capped ~28%. Now: BM=BN=256,
//   BK=64, 8 waves (2Mx4N), 128x64/wave, 4 phases/tile (phase p -> mf{2p,2p+1};
//   bfr read once in phase 0, held in regs). LDS 128KiB: A 4 half-slots
//   [par][half] 128x64 + B 2 slots [par] 256x64. Staging: A(t+1) in phases
//   0-1, B(t+2) in phases 2-3 (B slot freed by phase-0 reads) -> boundary
//   wait = counted vmcnt(4), never 0 in-loop. Swizzle/setprio/XCD-panel
//   mapping unchanged from R8 (verified: 0 bank conflicts, FETCH 49MB).
// attn (R6): paired Q-tiles, triple-buffered K/V ring, exp2 softmax (unchanged).
// Workspace: xb 16MB (aliased by Vt after QKV GEMM) | wat 6MB | wpt 2MB |
//            qkv 48MB | attn 16MB  = 88 MB
// ---------------------------------------------------------------------------

typedef uint16_t u16;
typedef __bf16 bf16x8 __attribute__((ext_vector_type(8)));
typedef __bf16 bf16x4 __attribute__((ext_vector_type(4)));
typedef short s16x4 __attribute__((ext_vector_type(4)));
typedef float f32x4 __attribute__((ext_vector_type(4)));

#define S_LEN 2048
#define DMODEL 1024
#define NHEAD 16
#define HDIM 64
#define MTOT 8192   // B*S
#define NQKV 3072

__device__ __forceinline__ u16 f2bf(float f) {
    union { float f; uint32_t u; } v; v.f = f;
    uint32_t u = v.u;
    return (u16)((u + 0x7fffu + ((u >> 16) & 1u)) >> 16);  // RNE
}

__device__ __forceinline__ s16x4 bits4(bf16x4 v) {
    union { bf16x4 b; s16x4 s; } u; u.b = v; return u.s;
}

// D = A*B + C, 16x16x16 bf16 (A,B: 4 bf16/lane, k = q4*4+j)
__device__ __forceinline__ f32x4 mfma16(bf16x4 a, bf16x4 b, f32x4 c) {
    return __builtin_amdgcn_mfma_f32_16x16x16bf16_1k(bits4(a), bits4(b), c, 0, 0, 0);
}

__device__ __forceinline__ void async_load16(const void* g, void* l) {
    __builtin_amdgcn_global_load_lds(
        (__attribute__((address_space(1))) void*)g,
        (__attribute__((address_space(3))) void*)l,
        16, 0, 0);
}

// ---- prep: fp32 -> bf16 (vectorized) --------------------------------------
__global__ void convert_x_kernel(const float4* __restrict__ in, ushort4* __restrict__ out, int n4) {
    int i = blockIdx.x * 256 + threadIdx.x;
    if (i < n4) {
        float4 f = in[i];
        ushort4 o;
        o.x = f2bf(f.x); o.y = f2bf(f.y); o.z = f2bf(f.z); o.w = f2bf(f.w);
        out[i] = o;
    }
}

// ---- prep: transpose + convert: in (R x C) fp32 -> out (C x R) bf16 --------
__global__ void transpose_bf16_kernel(const float* __restrict__ in, u16* __restrict__ out, int R, int C) {
    __shared__ float tile[64][65];
    int r0 = blockIdx.y * 64, c0 = blockIdx.x * 64;
    #pragma unroll
    for (int i = 0; i < 16; ++i) {
        int idx = threadIdx.x + i * 256;
        int r = idx >> 6, c = idx & 63;
        tile[r][c] = in[(size_t)(r0 + r) * C + c0 + c];
    }
    __syncthreads();
    #pragma unroll
    for (int i = 0; i < 16; ++i) {
        int idx = threadIdx.x + i * 256;
        int c = idx >> 6, r = idx & 63;
        out[(size_t)(c0 + c) * R + r0 + r] = f2bf(tile[r][c]);
    }
}

// ---- V transpose: qkv V-section (token-major) -> Vt[bh][d][s] --------------
__global__ void transpose_v_kernel(const u16* __restrict__ qkv, u16* __restrict__ vt) {
    __shared__ u16 tile[64 * 66];
    const int tid = threadIdx.x;
    const int stile = blockIdx.x, bh = blockIdx.y;
    const int b = bh >> 4, h = bh & 15;
    const u16* src = qkv + ((size_t)b * S_LEN + stile * 64) * NQKV + 2 * DMODEL + h * HDIM;
    #pragma unroll
    for (int it = 0; it < 2; ++it) {
        int item = it * 256 + tid;
        int s = item >> 3, d0 = (item & 7) * 8;
        bf16x8 v = *(const bf16x8*)(src + (size_t)s * NQKV + d0);
        const u16* vu = (const u16*)&v;
        #pragma unroll
        for (int j = 0; j < 8; ++j) tile[(d0 + j) * 66 + s] = vu[j];
    }
    __syncthreads();
    #pragma unroll
    for (int it = 0; it < 2; ++it) {
        int item = it * 256 + tid;
        int d = item >> 3, s0 = (item & 7) * 8;
        union { u16 u[8]; uint4 v; } pk;
        #pragma unroll
        for (int j = 0; j < 8; ++j) pk.u[j] = tile[d * 66 + s0 + j];
        *(uint4*)(vt + ((size_t)bh * 64 + d) * S_LEN + stile * 64 + s0) = pk.v;
    }
}

// ---- GEMM256SQ: C[M,N] = A[M,K] @ Bt[N,K]^T + bias -------------------------
// BM=BN=256, BK=64; 512 threads = 8 waves (wm=wave>>2 in M, wn=wave&3 in N),
// per-wave output 128x64 (mf 0..7, nf 0..3, 16x16x32 MFMA, acc = 32 f32x4).
// LDS 128KiB: A half-slots [par][half] of 128x64 bf16 (16KB each, wave wm
// reads only half wm); B slots [par] of 256x64 (32KB). Chunk-XOR swizzle
// (chunk ^= row&7): linear LDS dest + inverse-swizzled global src + swizzled
// ds_read (both-sides rule) -> conflict-free ds_read_b128.
// Per K-tile: 4 phases; phase p: {afr reads for mf{2p,2p+1} (+bfr 8 reads in
// p0, held in regs all tile) | 1 staged half-tile | barrier | setprio(1) +
// 16 MFMA + setprio(0) | barrier}. Staging: p0/p1 -> A(t+1) halves (slots
// freed in tile t-1); p2/p3 -> B(t+2) halves into B[par] (freed by p0 reads).
// Boundary: vmcnt(4) (B(t+2)'s 4 loads stay in flight), never 0 in-loop.
// Block mapping: xcd = bid&7 owns a fixed 4-mb-row A panel (2MB, L2-resident)
// and sweeps nb. Requires M%256==0, N%256==0, K%64==0, grid%8==0, M/256>=8.
template<bool OUT_BF16>
__global__ __launch_bounds__(512, 2) void gemm256sq(
    const u16* __restrict__ A, const u16* __restrict__ Bt,
    const float* __restrict__ bias, void* __restrict__ C,
    int M, int N, int K)
{
    __shared__ __attribute__((aligned(16))) u16 sm[65536];   // 128 KiB
    u16* const As = sm;            // 4 x 8192 u16: slot (par*2+half)
    u16* const Bs = sm + 32768;    // 2 x 16384 u16: slot par

    const int tid = threadIdx.x;
    const int wave = tid >> 6, lane = tid & 63;
    const int l15 = lane & 15, q4 = lane >> 4;
    const int wm = wave >> 2, wn = wave & 3;

    // XCD-resident A-panel mapping
    const int bid = (int)blockIdx.x;
    const int xcd = bid & 7;
    const int lx  = bid >> 3;
    const int MB  = M >> 8;                // 32
    const int PM  = MB >> 3;               // 4 rows per XCD panel
    const int nb  = lx / PM;
    const int mb  = xcd * PM + (lx - nb * PM);
    const int m0 = mb << 8, n0 = nb << 8;

    const u16* Ag = A + (size_t)m0 * K;
    const u16* Bg = Bt + (size_t)n0 * K;

    // staging: per thread 2x16B per half-tile; linear LDS dest, swizzled src
    const int srow = tid >> 3;
    const size_t goff0 = (size_t)srow * K + (size_t)(((tid & 7) ^ (srow & 7)) * 8);
    const size_t goff1 = goff0 + (size_t)64 * K;
    const int ldso = tid * 8;

    // ds_read chunk offsets (u16 units); frag row % 8 == l15 & 7
    const int ck0 = (q4 ^ (l15 & 7)) * 8;
    const int ck1 = ((4 + q4) ^ (l15 & 7)) * 8;
    const int rb0 = (wn * 64 + l15) * 64;   // B row base for nf=0

    f32x4 acc[8][4] = {};
    const int T = K >> 6;

#define STAGE_A(t_, h_) do { \
    const u16* g_ = Ag + (size_t)(h_) * 128 * K + (size_t)(t_) * 64; \
    u16* d_ = As + (((t_) & 1) * 2 + (h_)) * 8192; \
    async_load16(g_ + goff0, d_ + ldso); \
    async_load16(g_ + goff1, d_ + ldso + 4096); \
} while (0)

#define STAGE_B(t_, h_) do { \
    const u16* g_ = Bg + (size_t)(h_) * 128 * K + (size_t)(t_) * 64; \
    u16* d_ = Bs + ((t_) & 1) * 16384 + (h_) * 8192; \
    async_load16(g_ + goff0, d_ + ldso); \
    async_load16(g_ + goff1, d_ + ldso + 4096); \
} while (0)

#define LOAD_AF(P_) do { \
    af[0][0] = *(const bf16x8*)(Ah + ((2 * (P_)) * 16 + l15) * 64 + ck0); \
    af[0][1] = *(const bf16x8*)(Ah + ((2 * (P_)) * 16 + l15) * 64 + ck1); \
    af[1][0] = *(const bf16x8*)(Ah + ((2 * (P_) + 1) * 16 + l15) * 64 + ck0); \
    af[1][1] = *(const bf16x8*)(Ah + ((2 * (P_) + 1) * 16 + l15) * 64 + ck1); \
} while (0)

#define PHASE_MFMA(P_) do { \
    asm volatile("s_barrier" ::: "memory"); \
    __builtin_amdgcn_s_setprio(1); \
    _Pragma("unroll") \
    for (int i_ = 0; i_ < 2; ++i_) \
        _Pragma("unroll") \
        for (int nf_ = 0; nf_ < 4; ++nf_) \
            _Pragma("unroll") \
            for (int kk_ = 0; kk_ < 2; ++kk_) \
                acc[2 * (P_) + i_][nf_] = __builtin_amdgcn_mfma_f32_16x16x32_bf16( \
                    af[i_][kk_], bfr[nf_][kk_], acc[2 * (P_) + i_][nf_], 0, 0, 0); \
    __builtin_amdgcn_s_setprio(0); \
} while (0)

    // prologue: tile0 {A0,A1,B0h0,B0h1} + B(1) both halves; wait tile0 only
    STAGE_A(0, 0); STAGE_A(0, 1); STAGE_B(0, 0); STAGE_B(0, 1);
    if (T > 1) {
        STAGE_B(1, 0); STAGE_B(1, 1);
        asm volatile("s_waitcnt vmcnt(4)" ::: "memory");
    } else {
        asm volatile("s_waitcnt vmcnt(0)" ::: "memory");
    }
    asm volatile("s_barrier" ::: "memory");

    for (int t = 0; t < T; ++t) {
        const int par = t & 1;
        const u16* Ah = As + (par * 2 + wm) * 8192;   // this wave's A half
        const u16* Bl = Bs + par * 16384;

        bf16x8 af[2][2], bfr[4][2];

        // ---- phase 0: bfr (held all tile) + afr{0,1}; stage A(t+1).h0 ------
        #pragma unroll
        for (int nf = 0; nf < 4; ++nf) {
            bfr[nf][0] = *(const bf16x8*)(Bl + rb0 + nf * (16 * 64) + ck0);
            bfr[nf][1] = *(const bf16x8*)(Bl + rb0 + nf * (16 * 64) + ck1);
        }
        LOAD_AF(0);
        if (t + 1 < T) STAGE_A(t + 1, 0);
        PHASE_MFMA(0);
        asm volatile("s_barrier" ::: "memory");

        // ---- phase 1: afr{2,3}; stage A(t+1).h1 ----------------------------
        LOAD_AF(1);
        if (t + 1 < T) STAGE_A(t + 1, 1);
        PHASE_MFMA(1);
        asm volatile("s_barrier" ::: "memory");

        // ---- phase 2: afr{4,5}; stage B(t+2).h0 into B[par] (freed by p0) --
        LOAD_AF(2);
        if (t + 2 < T) STAGE_B(t + 2, 0);
        PHASE_MFMA(2);
        asm volatile("s_barrier" ::: "memory");

        // ---- phase 3: afr{6,7}; stage B(t+2).h1 ----------------------------
        LOAD_AF(3);
        if (t + 2 < T) STAGE_B(t + 2, 1);
        PHASE_MFMA(3);
        // boundary: A(t+1) complete; B(t+2)'s 4 loads stay in flight
        if (t + 1 < T) {
            if (t + 2 < T) asm volatile("s_waitcnt vmcnt(4)" ::: "memory");
            else           asm volatile("s_waitcnt vmcnt(0)" ::: "memory");
            asm volatile("s_barrier" ::: "memory");
        }
    }

#undef STAGE_A
#undef STAGE_B
#undef LOAD_AF
#undef PHASE_MFMA

    // epilogue
    #pragma unroll
    for (int mf = 0; mf < 8; ++mf) {
        const int row = m0 + wm * 128 + mf * 16 + q4 * 4;
        #pragma unroll
        for (int nf = 0; nf < 4; ++nf) {
            const int col = n0 + wn * 64 + nf * 16 + l15;
            const float bv = bias[col];
            #pragma unroll
            for (int r = 0; r < 4; ++r) {
                float v = acc[mf][nf][r] + bv;
                if (OUT_BF16) ((u16*)C)[(size_t)(row + r) * N + col] = f2bf(v);
                else          ((float*)C)[(size_t)(row + r) * N + col] = v;
            }
        }
    }
}

// ---- flash attention R6 ----------------------------------------------------
// One Q-tile pass (128 q-rows at qt). Triple-buffered K/V, prefetch-2,
// S^T = K·Q^T -> exp2 -> P^T B-frags in registers -> O^T = V^T·P^T.
__device__ __forceinline__ void stage_tiles(
    const u16* __restrict__ qkv, const u16* __restrict__ vt,
    size_t base, int bh, int h, int w, int srow8, int schunk,
    int kt, u16* __restrict__ KsB, u16* __restrict__ VsB)
{
    #pragma unroll
    for (int q = 0; q < 2; ++q) {
        int rloc = w * 16 + q * 8 + srow8;
        int sc = ((schunk ^ (rloc & 7)) * 8);
        async_load16(qkv + (base + (size_t)kt * 64 + rloc) * (size_t)NQKV + DMODEL + h * HDIM + sc,
                     KsB + (w * 16 + q * 8) * 64);
        async_load16(vt + ((size_t)bh * 64 + rloc) * S_LEN + kt * 64 + sc,
                     VsB + (w * 16 + q * 8) * 64);
    }
}

__device__ __forceinline__ void attn_pass(
    int qt, const u16* __restrict__ qkv, const u16* __restrict__ vt,
    __bf16* __restrict__ outb, u16 (*Ks)[64 * 64], u16 (*Vs)[64 * 64],
    int w, int lane, int bh, int h, size_t base)
{
    const int l15 = lane & 15, q4 = lane >> 4;
    const int srow8 = lane >> 3, schunk = lane & 7;

    // Q fragments for both halves ([n=q=l15][k=d=q4*8+j]); scale folds
    // 1/sqrt(64) * log2(e) so P = 2^(K·Q^T) == e^(K·Q^T/8).
    const float QSCALE = 0.125f * 1.44269504f;
    bf16x8 qf[2][2];
    #pragma unroll
    for (int mh = 0; mh < 2; ++mh) {
        int qrow = qt * 128 + mh * 64 + w * 16 + l15;
        #pragma unroll
        for (int kc = 0; kc < 2; ++kc) {
            bf16x8 raw = *(const bf16x8*)(qkv + (base + qrow) * (size_t)NQKV + h * HDIM + kc * 32 + q4 * 8);
            bf16x8 sc;
            #pragma unroll
            for (int j = 0; j < 8; ++j) sc[j] = (__bf16)((float)raw[j] * QSCALE);
            qf[mh][kc] = sc;
        }
    }

    bf16x4 ones4;
    #pragma unroll
    for (int j = 0; j < 4; ++j) ones4[j] = (__bf16)1.0f;

    f32x4 o0[4] = {}, o1[4] = {};   // O^T: [d-tile mt][q=l15], rows d=q4*4+r
    f32x4 la0 = {}, la1 = {};       // l[q=l15]

    const int ktlast = 2 * qt + 1;  // tail tile (half-0 fully masked)

    __syncthreads();                // protect LDS reuse across passes
    stage_tiles(qkv, vt, base, bh, h, w, srow8, schunk, 0, Ks[0], Vs[0]);
    if (ktlast >= 1)
        stage_tiles(qkv, vt, base, bh, h, w, srow8, schunk, 1, Ks[1], Vs[1]);

    for (int kt = 0; kt <= 2 * qt; ++kt) {
        const int buf = kt % 3;
        __syncthreads();            // kt,kt+1 staged; reads of buf (kt+2)%3 done
        int pf = kt + 2;
        if (pf <= ktlast)
            stage_tiles(qkv, vt, base, bh, h, w, srow8, schunk, pf, Ks[pf % 3], Vs[pf % 3]);

        // S^T = K·Q^T; kf shared across halves
        f32x4 st0[4] = {}, st1[4] = {};
        #pragma unroll
        for (int nt = 0; nt < 4; ++nt) {
            int n = nt * 16 + l15;      // key row in Ks
            #pragma unroll
            for (int kc = 0; kc < 2; ++kc) {
                int ch = (((kc * 4 + q4) ^ (n & 7)) * 8);
                bf16x8 kf = *(const bf16x8*)(&Ks[buf][n * 64 + ch]);
                st0[nt] = __builtin_amdgcn_mfma_f32_16x16x32_bf16(kf, qf[0][kc], st0[nt], 0, 0, 0);
                st1[nt] = __builtin_amdgcn_mfma_f32_16x16x32_bf16(kf, qf[1][kc], st1[nt], 0, 0, 0);
            }
        }

        if (kt == 2 * qt) {             // diagonal for half 0 (uniform branch)
            #pragma unroll
            for (int nt = 0; nt < 4; ++nt)
                #pragma unroll
                for (int r = 0; r < 4; ++r) {
                    int keyl = nt * 16 + q4 * 4 + r;
                    if (keyl > w * 16 + l15) st0[nt][r] = -1e30f;
                }
        }

        // P^T = 2^(S^T) packed to bf16x4 B-frags (k = q4*4+j), in registers
        bf16x4 pb0[4], pb1[4];
        #pragma unroll
        for (int nt = 0; nt < 4; ++nt)
            #pragma unroll
            for (int r = 0; r < 4; ++r) {
                pb0[nt][r] = (__bf16)__builtin_amdgcn_exp2f(st0[nt][r]);
                pb1[nt][r] = (__bf16)__builtin_amdgcn_exp2f(st1[nt][r]);
            }

        // O^T += V^T · P^T  (vf shared across halves); l += ones · P^T
        #pragma unroll
        for (int nt = 0; nt < 4; ++nt) {
            #pragma unroll
            for (int mt = 0; mt < 4; ++mt) {
                int row = mt * 16 + l15;                       // d row in Vs
                int ch = (nt * 2 + (q4 >> 1)) ^ (row & 7);
                bf16x4 vf = *(const bf16x4*)(&Vs[buf][row * 64 + ch * 8 + (q4 & 1) * 4]);
                o0[mt] = mfma16(vf, pb0[nt], o0[mt]);
                o1[mt] = mfma16(vf, pb1[nt], o1[mt]);
            }
            la0 = mfma16(ones4, pb0[nt], la0);
            la1 = mfma16(ones4, pb1[nt], la1);
        }
    }

    // ---- tail tile ktlast: half 0 fully masked; half 1 only ----------------
    {
        const int buf = ktlast % 3;
        __syncthreads();

        f32x4 st1[4] = {};
        #pragma unroll
        for (int nt = 0; nt < 4; ++nt) {
            int n = nt * 16 + l15;
            #pragma unroll
            for (int kc = 0; kc < 2; ++kc) {
                int ch = (((kc * 4 + q4) ^ (n & 7)) * 8);
                bf16x8 kf = *(const bf16x8*)(&Ks[buf][n * 64 + ch]);
                st1[nt] = __builtin_amdgcn_mfma_f32_16x16x32_bf16(kf, qf[1][kc], st1[nt], 0, 0, 0);
            }
        }
        bf16x4 pb1[4];
        #pragma unroll
        for (int nt = 0; nt < 4; ++nt)
            #pragma unroll
            for (int r = 0; r < 4; ++r) {
                int keyl = nt * 16 + q4 * 4 + r;
                float s = (keyl > w * 16 + l15) ? -1e30f : st1[nt][r];
                pb1[nt][r] = (__bf16)__builtin_amdgcn_exp2f(s);
            }
        #pragma unroll
        for (int nt = 0; nt < 4; ++nt) {
            #pragma unroll
            for (int mt = 0; mt < 4; ++mt) {
                int row = mt * 16 + l15;
                int ch = (nt * 2 + (q4 >> 1)) ^ (row & 7);
                bf16x4 vf = *(const bf16x4*)(&Vs[buf][row * 64 + ch * 8 + (q4 & 1) * 4]);
                o1[mt] = mfma16(vf, pb1[nt], o1[mt]);
            }
            la1 = mfma16(ones4, pb1[nt], la1);
        }
    }

    // epilogue: lane holds O^T[d = mt*16+q4*4+r][q=l15]; packed 8B stores
    float inv0 = 1.0f / la0[0], inv1 = 1.0f / la1[0];
    int row0 = qt * 128 + w * 16 + l15;
    int row1 = row0 + 64;
    #pragma unroll
    for (int mt = 0; mt < 4; ++mt) {
        union { __bf16 b[4]; ushort4 v; } p0, p1;
        #pragma unroll
        for (int r = 0; r < 4; ++r) {
            p0.b[r] = (__bf16)(o0[mt][r] * inv0);
            p1.b[r] = (__bf16)(o1[mt][r] * inv1);
        }
        int col = h * HDIM + mt * 16 + q4 * 4;
        *(ushort4*)(&outb[(base + row0) * (size_t)DMODEL + col]) = p0.v;
        *(ushort4*)(&outb[(base + row1) * (size_t)DMODEL + col]) = p1.v;
    }
}

// block = (bx, bh): processes Q-tiles qt = NT-1-bx and qt = bx (34 K-iters
// total for every block -> perfect load balance). gridDim.x = NT/2 = 8.
__global__ __launch_bounds__(256, 3) void attn_kernel(
    const u16* __restrict__ qkv, const u16* __restrict__ vt, u16* __restrict__ out)
{
    __shared__ __attribute__((aligned(16))) u16 Ks[3][64 * 64];
    __shared__ __attribute__((aligned(16))) u16 Vs[3][64 * 64];

    const int tid = threadIdx.x;
    const int w = tid >> 6, lane = tid & 63;
    const int bh = blockIdx.y;
    const int b = bh >> 4, h = bh & 15;
    const size_t base = (size_t)b * S_LEN;
    const int NT = (int)gridDim.x * 2;           // 16

    attn_pass(NT - 1 - (int)blockIdx.x, qkv, vt, (__bf16*)out, Ks, Vs, w, lane, bh, h, base);
    attn_pass((int)blockIdx.x,          qkv, vt, (__bf16*)out, Ks, Vs, w, lane, bh, h, base);
}

extern "C" void kernel_launch(void* const* d_in, const int* in_sizes, int n_in,
                              void* d_out, int out_size, void* d_ws, size_t ws_size,
                              hipStream_t stream) {
    const float* x      = (const float*)d_in[0];
    // d_in[1] = mask (causal tril) — implemented structurally, not read
    const float* w_attn = (const float*)d_in[2];
    const float* b_attn = (const float*)d_in[3];
    const float* w_proj = (const float*)d_in[4];
    const float* b_proj = (const float*)d_in[5];

    u16* xb   = (u16*)d_ws;                                   // 8192x1024 (dead after QKV GEMM)
    u16* wat  = xb  + (size_t)MTOT * DMODEL;                  // 3072x1024
    u16* wpt  = wat + (size_t)NQKV * DMODEL;                  // 1024x1024
    u16* qkv  = wpt + (size_t)DMODEL * DMODEL;                // 8192x3072
    u16* attn = qkv + (size_t)MTOT * NQKV;                    // 8192x1024
    u16* vt   = xb;                                           // Vt[64 bh][64 d][2048 s] aliases xb

    convert_x_kernel<<<(MTOT * DMODEL / 4 + 255) / 256, 256, 0, stream>>>(
        (const float4*)x, (ushort4*)xb, MTOT * DMODEL / 4);
    transpose_bf16_kernel<<<dim3(NQKV / 64, DMODEL / 64), 256, 0, stream>>>(w_attn, wat, DMODEL, NQKV);
    transpose_bf16_kernel<<<dim3(DMODEL / 64, DMODEL / 64), 256, 0, stream>>>(w_proj, wpt, DMODEL, DMODEL);

    gemm256sq<true><<<dim3((MTOT / 256) * (NQKV / 256)), 512, 0, stream>>>(
        xb, wat, b_attn, (void*)qkv, MTOT, NQKV, DMODEL);

    transpose_v_kernel<<<dim3(S_LEN / 64, 4 * NHEAD), 256, 0, stream>>>(qkv, vt);

    attn_kernel<<<dim3(S_LEN / 256, 4 * NHEAD), 256, 0, stream>>>(qkv, vt, attn);

    gemm256sq<false><<<dim3((MTOT / 256) * (DMODEL / 256)), 512, 0, stream>>>(
        attn, wpt, b_proj, d_out, MTOT, DMODEL, DMODEL);
}

// Round 4
// 273.717 us; speedup vs baseline: 1.0181x; 1.0181x over previous
//
#include <hip/hip_runtime.h>
#include <hip/hip_bf16.h>
#include <stdint.h>

// ---------------------------------------------------------------------------
// CausalSelfAttention: x(4,2048,1024) fp32 -> out fp32
// qkv = x@w_attn+b_attn; flash-attn causal (H=16,hd=64); out = attn@w_proj+b_proj
// R10: gemm32 — MFMA shape 16x16x32 -> 32x32x16 (measured pipe 2495 vs 2075 TF,
//   half the instruction count; LDS traffic unchanged but MFMA time drops
//   2512->2066 cyc/CU-tile). Template<MSUB>: per-wave tile MSUB*32 x 64.
//   QKV: MSUB=4 (BM=BN=256, waves 2Mx4N, 128x64/wave, grid 384).
//   proj: MSUB=2 (BM=256,BN=128, waves 4Mx2N, 64x64/wave, grid 256 = 1/CU
//   exact — R9's proj grid of 128 idled half the chip).
//   Per K-tile 4 phases = k-subtiles; phase p: {reads | stage | bar | prio+
//   (MSUB*2) MFMA +prio | bar}. bfr (8 frags) read in p0/p1, held in regs;
//   A(t+1) halves staged p0/p1, B(t+2) staged p2/p3 into the live-parity B
//   buffer (safe: all B reads drained by lgkmcnt(0) at end of p1). Boundary
//   wait = counted vmcnt(4/2) — never 0 in-loop. Swizzle (chunk^=row&7,
//   both-sides), XCD A-panel mapping (FETCH 41MB verified) unchanged.
// attn (R6): paired Q-tiles, triple-buffered K/V ring, exp2 softmax (unchanged).
// Workspace: xb 16MB (aliased by Vt after QKV GEMM) | wat 6MB | wpt 2MB |
//            qkv 48MB | attn 16MB  = 88 MB
// ---------------------------------------------------------------------------

typedef uint16_t u16;
typedef __bf16 bf16x8 __attribute__((ext_vector_type(8)));
typedef __bf16 bf16x4 __attribute__((ext_vector_type(4)));
typedef short s16x4 __attribute__((ext_vector_type(4)));
typedef float f32x4 __attribute__((ext_vector_type(4)));
typedef float f32x16 __attribute__((ext_vector_type(16)));

#define S_LEN 2048
#define DMODEL 1024
#define NHEAD 16
#define HDIM 64
#define MTOT 8192   // B*S
#define NQKV 3072

__device__ __forceinline__ u16 f2bf(float f) {
    union { float f; uint32_t u; } v; v.f = f;
    uint32_t u = v.u;
    return (u16)((u + 0x7fffu + ((u >> 16) & 1u)) >> 16);  // RNE
}

__device__ __forceinline__ s16x4 bits4(bf16x4 v) {
    union { bf16x4 b; s16x4 s; } u; u.b = v; return u.s;
}

// D = A*B + C, 16x16x16 bf16 (A,B: 4 bf16/lane, k = q4*4+j)
__device__ __forceinline__ f32x4 mfma16(bf16x4 a, bf16x4 b, f32x4 c) {
    return __builtin_amdgcn_mfma_f32_16x16x16bf16_1k(bits4(a), bits4(b), c, 0, 0, 0);
}

// D = A*B + C, 32x32x16 bf16 (A,B: 8 bf16/lane; C/D 16 f32/lane)
__device__ __forceinline__ f32x16 mfma32(bf16x8 a, bf16x8 b, f32x16 c) {
    return __builtin_amdgcn_mfma_f32_32x32x16_bf16(a, b, c, 0, 0, 0);
}

__device__ __forceinline__ void async_load16(const void* g, void* l) {
    __builtin_amdgcn_global_load_lds(
        (__attribute__((address_space(1))) void*)g,
        (__attribute__((address_space(3))) void*)l,
        16, 0, 0);
}

// ---- prep: fp32 -> bf16 (vectorized) --------------------------------------
__global__ void convert_x_kernel(const float4* __restrict__ in, ushort4* __restrict__ out, int n4) {
    int i = blockIdx.x * 256 + threadIdx.x;
    if (i < n4) {
        float4 f = in[i];
        ushort4 o;
        o.x = f2bf(f.x); o.y = f2bf(f.y); o.z = f2bf(f.z); o.w = f2bf(f.w);
        out[i] = o;
    }
}

// ---- prep: transpose + convert: in (R x C) fp32 -> out (C x R) bf16 --------
__global__ void transpose_bf16_kernel(const float* __restrict__ in, u16* __restrict__ out, int R, int C) {
    __shared__ float tile[64][65];
    int r0 = blockIdx.y * 64, c0 = blockIdx.x * 64;
    #pragma unroll
    for (int i = 0; i < 16; ++i) {
        int idx = threadIdx.x + i * 256;
        int r = idx >> 6, c = idx & 63;
        tile[r][c] = in[(size_t)(r0 + r) * C + c0 + c];
    }
    __syncthreads();
    #pragma unroll
    for (int i = 0; i < 16; ++i) {
        int idx = threadIdx.x + i * 256;
        int c = idx >> 6, r = idx & 63;
        out[(size_t)(c0 + c) * R + r0 + r] = f2bf(tile[r][c]);
    }
}

// ---- V transpose: qkv V-section (token-major) -> Vt[bh][d][s] --------------
__global__ void transpose_v_kernel(const u16* __restrict__ qkv, u16* __restrict__ vt) {
    __shared__ u16 tile[64 * 66];
    const int tid = threadIdx.x;
    const int stile = blockIdx.x, bh = blockIdx.y;
    const int b = bh >> 4, h = bh & 15;
    const u16* src = qkv + ((size_t)b * S_LEN + stile * 64) * NQKV + 2 * DMODEL + h * HDIM;
    #pragma unroll
    for (int it = 0; it < 2; ++it) {
        int item = it * 256 + tid;
        int s = item >> 3, d0 = (item & 7) * 8;
        bf16x8 v = *(const bf16x8*)(src + (size_t)s * NQKV + d0);
        const u16* vu = (const u16*)&v;
        #pragma unroll
        for (int j = 0; j < 8; ++j) tile[(d0 + j) * 66 + s] = vu[j];
    }
    __syncthreads();
    #pragma unroll
    for (int it = 0; it < 2; ++it) {
        int item = it * 256 + tid;
        int d = item >> 3, s0 = (item & 7) * 8;
        union { u16 u[8]; uint4 v; } pk;
        #pragma unroll
        for (int j = 0; j < 8; ++j) pk.u[j] = tile[d * 66 + s0 + j];
        *(uint4*)(vt + ((size_t)bh * 64 + d) * S_LEN + stile * 64 + s0) = pk.v;
    }
}

// ---- GEMM32: C[M,N] = A[M,K] @ Bt[N,K]^T + bias, 32x32x16 MFMA -------------
// BM=256, BN=64*MSUB, BK=64; 512 threads = 8 waves (wm=wave/MSUB along M,
// wn=wave%MSUB along N); per-wave output (MSUB*32) x 64, acc = MSUB*2 f32x16.
// Fragment layouts (32x32x16): A row=l&31, k=(l>>5)*8+j; B col=l&31 same k;
// C/D col=l&31, row=(reg&3)+8*(reg>>2)+4*(l>>5).
// LDS: A 4 half-slots [par][half] 128x64 (16KB); B 2 slots [par] BNx64.
// Chunk-XOR swizzle (chunk ^= row&7): linear LDS dest (global_load_lds) +
// inverse-swizzled global src + swizzled ds_read -> conflict-free b128.
// Phases p=0..3 (k-sub p): reads {p0: bfr k0,k1 + af | p1: bfr k2,k3 + af |
// p2/p3: af}; stage {p0/p1: A(t+1) halves | p2/p3: B(t+2) into B[par], safe
// because all B reads drained by lgkmcnt(0) at end of p1}; barrier;
// setprio(1) + MSUB*2 MFMA + setprio(0); barrier. Boundary: vmcnt(2*NBH)
// (B(t+2) stays in flight), never 0 in-loop.
// Mapping: xcd=bid&7 owns fixed 4-mb-row A panel (2MB, L2-resident), sweeps nb.
template<int MSUB, bool OUT_BF16>
__global__ __launch_bounds__(512, 2) void gemm32(
    const u16* __restrict__ A, const u16* __restrict__ Bt,
    const float* __restrict__ bias, void* __restrict__ C,
    int M, int N, int K)
{
    constexpr int NBH = MSUB / 2;          // B half-tiles per K-tile (2 or 1)
    constexpr int BSLOT = 64 * MSUB * 64;  // u16 per B parity buffer
    __shared__ __attribute__((aligned(16))) u16 sm[32768 + 2 * BSLOT];
    u16* const As = sm;                    // 4 x 8192 u16: slot (par*2+half)
    u16* const Bs = sm + 32768;            // 2 x BSLOT u16: slot par

    const int tid = threadIdx.x;
    const int wave = tid >> 6, lane = tid & 63;
    const int l31 = lane & 31, hi = lane >> 5;
    const int wm = wave / MSUB, wn = wave % MSUB;
    const int wmbase = wm * MSUB * 32;

    // XCD-resident A-panel mapping
    const int bid = (int)blockIdx.x;
    const int xcd = bid & 7;
    const int lx  = bid >> 3;
    const int MB  = M >> 8;                // 32
    const int PM  = MB >> 3;               // 4 rows per XCD panel
    const int nb  = lx / PM;
    const int mb  = xcd * PM + (lx - nb * PM);
    const int m0 = mb << 8, n0 = nb * 64 * MSUB;

    const u16* Ag = A + (size_t)m0 * K;
    const u16* Bg = Bt + (size_t)n0 * K;

    // staging: per thread 2x16B per 128x64 half-tile; linear LDS dest,
    // inverse-swizzled global source
    const int srow = tid >> 3;
    const size_t goff0 = (size_t)srow * K + (size_t)(((tid & 7) ^ (srow & 7)) * 8);
    const size_t goff1 = goff0 + (size_t)64 * K;
    const int ldso = tid * 8;

    // swizzled ds_read chunk offsets per k-sub (u16 units); row%8 == lane&7
    const int ck[4] = { ((0 + hi) ^ (lane & 7)) * 8, ((2 + hi) ^ (lane & 7)) * 8,
                        ((4 + hi) ^ (lane & 7)) * 8, ((6 + hi) ^ (lane & 7)) * 8 };
    const int AH = wmbase >> 7;                 // this wave's A half-slot
    const int abase = (wmbase & 127) + l31;     // A row within half
    const int bbase = wn * 64 + l31;            // B row within tile

    f32x16 acc[MSUB][2] = {};
    const int T = K >> 6;

#define STAGE_A(t_, h_) do { \
    const u16* ga_ = Ag + (size_t)(h_) * 128 * K + (size_t)(t_) * 64; \
    u16* da_ = As + (((t_) & 1) * 2 + (h_)) * 8192; \
    async_load16(ga_ + goff0, da_ + ldso); \
    async_load16(ga_ + goff1, da_ + ldso + 4096); \
} while (0)

#define STAGE_B(t_, h_) do { \
    const u16* gb_ = Bg + (size_t)(h_) * 128 * K + (size_t)(t_) * 64; \
    u16* db_ = Bs + ((t_) & 1) * BSLOT + (h_) * 8192; \
    async_load16(gb_ + goff0, db_ + ldso); \
    async_load16(gb_ + goff1, db_ + ldso + 4096); \
} while (0)

#define LOAD_AF(S_) do { \
    _Pragma("unroll") \
    for (int i_ = 0; i_ < MSUB; ++i_) \
        af[i_] = *(const bf16x8*)(Ah + (abase + i_ * 32) * 64 + ck[S_]); \
} while (0)

#define PHASE_MFMA(S_) do { \
    asm volatile("s_barrier" ::: "memory"); \
    __builtin_amdgcn_s_setprio(1); \
    _Pragma("unroll") \
    for (int i_ = 0; i_ < MSUB; ++i_) \
        _Pragma("unroll") \
        for (int n_ = 0; n_ < 2; ++n_) \
            acc[i_][n_] = mfma32(af[i_], bfr[n_][S_], acc[i_][n_]); \
    __builtin_amdgcn_s_setprio(0); \
} while (0)

    // prologue: A(0) both halves + B(0) + B(1); keep B(1) in flight
    STAGE_A(0, 0); STAGE_A(0, 1);
    STAGE_B(0, 0); if constexpr (NBH == 2) STAGE_B(0, 1);
    if (T > 1) {
        STAGE_B(1, 0); if constexpr (NBH == 2) STAGE_B(1, 1);
        if constexpr (NBH == 2) asm volatile("s_waitcnt vmcnt(4)" ::: "memory");
        else                    asm volatile("s_waitcnt vmcnt(2)" ::: "memory");
    } else {
        asm volatile("s_waitcnt vmcnt(0)" ::: "memory");
    }
    asm volatile("s_barrier" ::: "memory");

    for (int t = 0; t < T; ++t) {
        const int par = t & 1;
        const u16* Ah = As + (par * 2 + AH) * 8192;
        const u16* Bl = Bs + par * BSLOT;

        bf16x8 af[MSUB], bfr[2][4];

        // ---- phase 0: bfr k-subs 0,1 + af(k0); stage A(t+1).h0 -------------
        #pragma unroll
        for (int n_ = 0; n_ < 2; ++n_) {
            bfr[n_][0] = *(const bf16x8*)(Bl + (bbase + n_ * 32) * 64 + ck[0]);
            bfr[n_][1] = *(const bf16x8*)(Bl + (bbase + n_ * 32) * 64 + ck[1]);
        }
        LOAD_AF(0);
        if (t + 1 < T) STAGE_A(t + 1, 0);
        PHASE_MFMA(0);
        asm volatile("s_barrier" ::: "memory");

        // ---- phase 1: bfr k-subs 2,3 + af(k1); stage A(t+1).h1 -------------
        #pragma unroll
        for (int n_ = 0; n_ < 2; ++n_) {
            bfr[n_][2] = *(const bf16x8*)(Bl + (bbase + n_ * 32) * 64 + ck[2]);
            bfr[n_][3] = *(const bf16x8*)(Bl + (bbase + n_ * 32) * 64 + ck[3]);
        }
        LOAD_AF(1);
        if (t + 1 < T) STAGE_A(t + 1, 1);
        PHASE_MFMA(1);
        // drain ALL B ds_reads before any wave stages B(t+2) into Bs[par]
        asm volatile("s_waitcnt lgkmcnt(0)" ::: "memory");
        asm volatile("s_barrier" ::: "memory");

        // ---- phase 2: af(k2); stage B(t+2).h0 into B[par] ------------------
        LOAD_AF(2);
        if (t + 2 < T) STAGE_B(t + 2, 0);
        PHASE_MFMA(2);
        asm volatile("s_barrier" ::: "memory");

        // ---- phase 3: af(k3); stage B(t+2).h1 ------------------------------
        LOAD_AF(3);
        if constexpr (NBH == 2) { if (t + 2 < T) STAGE_B(t + 2, 1); }
        PHASE_MFMA(3);
        // boundary: A(t+1)+B(t+1) complete; B(t+2) loads stay in flight
        if (t + 1 < T) {
            if (t + 2 < T) {
                if constexpr (NBH == 2) asm volatile("s_waitcnt vmcnt(4)" ::: "memory");
                else                    asm volatile("s_waitcnt vmcnt(2)" ::: "memory");
            } else {
                asm volatile("s_waitcnt vmcnt(0)" ::: "memory");
            }
            asm volatile("s_barrier" ::: "memory");
        }
    }

#undef STAGE_A
#undef STAGE_B
#undef LOAD_AF
#undef PHASE_MFMA

    // epilogue: C/D col=l31, row=(reg&3)+8*(reg>>2)+4*hi
    #pragma unroll
    for (int i = 0; i < MSUB; ++i) {
        #pragma unroll
        for (int n = 0; n < 2; ++n) {
            const int col = n0 + wn * 64 + n * 32 + l31;
            const float bv = bias[col];
            #pragma unroll
            for (int g = 0; g < 4; ++g) {
                #pragma unroll
                for (int r = 0; r < 4; ++r) {
                    const int row = m0 + wmbase + i * 32 + g * 8 + r + 4 * hi;
                    float v = acc[i][n][g * 4 + r] + bv;
                    if (OUT_BF16) ((u16*)C)[(size_t)row * N + col] = f2bf(v);
                    else          ((float*)C)[(size_t)row * N + col] = v;
                }
            }
        }
    }
}

// ---- flash attention R6 ----------------------------------------------------
// One Q-tile pass (128 q-rows at qt). Triple-buffered K/V, prefetch-2,
// S^T = K·Q^T -> exp2 -> P^T B-frags in registers -> O^T = V^T·P^T.
__device__ __forceinline__ void stage_tiles(
    const u16* __restrict__ qkv, const u16* __restrict__ vt,
    size_t base, int bh, int h, int w, int srow8, int schunk,
    int kt, u16* __restrict__ KsB, u16* __restrict__ VsB)
{
    #pragma unroll
    for (int q = 0; q < 2; ++q) {
        int rloc = w * 16 + q * 8 + srow8;
        int sc = ((schunk ^ (rloc & 7)) * 8);
        async_load16(qkv + (base + (size_t)kt * 64 + rloc) * (size_t)NQKV + DMODEL + h * HDIM + sc,
                     KsB + (w * 16 + q * 8) * 64);
        async_load16(vt + ((size_t)bh * 64 + rloc) * S_LEN + kt * 64 + sc,
                     VsB + (w * 16 + q * 8) * 64);
    }
}

__device__ __forceinline__ void attn_pass(
    int qt, const u16* __restrict__ qkv, const u16* __restrict__ vt,
    __bf16* __restrict__ outb, u16 (*Ks)[64 * 64], u16 (*Vs)[64 * 64],
    int w, int lane, int bh, int h, size_t base)
{
    const int l15 = lane & 15, q4 = lane >> 4;
    const int srow8 = lane >> 3, schunk = lane & 7;

    // Q fragments for both halves ([n=q=l15][k=d=q4*8+j]); scale folds
    // 1/sqrt(64) * log2(e) so P = 2^(K·Q^T) == e^(K·Q^T/8).
    const float QSCALE = 0.125f * 1.44269504f;
    bf16x8 qf[2][2];
    #pragma unroll
    for (int mh = 0; mh < 2; ++mh) {
        int qrow = qt * 128 + mh * 64 + w * 16 + l15;
        #pragma unroll
        for (int kc = 0; kc < 2; ++kc) {
            bf16x8 raw = *(const bf16x8*)(qkv + (base + qrow) * (size_t)NQKV + h * HDIM + kc * 32 + q4 * 8);
            bf16x8 sc;
            #pragma unroll
            for (int j = 0; j < 8; ++j) sc[j] = (__bf16)((float)raw[j] * QSCALE);
            qf[mh][kc] = sc;
        }
    }

    bf16x4 ones4;
    #pragma unroll
    for (int j = 0; j < 4; ++j) ones4[j] = (__bf16)1.0f;

    f32x4 o0[4] = {}, o1[4] = {};   // O^T: [d-tile mt][q=l15], rows d=q4*4+r
    f32x4 la0 = {}, la1 = {};       // l[q=l15]

    const int ktlast = 2 * qt + 1;  // tail tile (half-0 fully masked)

    __syncthreads();                // protect LDS reuse across passes
    stage_tiles(qkv, vt, base, bh, h, w, srow8, schunk, 0, Ks[0], Vs[0]);
    if (ktlast >= 1)
        stage_tiles(qkv, vt, base, bh, h, w, srow8, schunk, 1, Ks[1], Vs[1]);

    for (int kt = 0; kt <= 2 * qt; ++kt) {
        const int buf = kt % 3;
        __syncthreads();            // kt,kt+1 staged; reads of buf (kt+2)%3 done
        int pf = kt + 2;
        if (pf <= ktlast)
            stage_tiles(qkv, vt, base, bh, h, w, srow8, schunk, pf, Ks[pf % 3], Vs[pf % 3]);

        // S^T = K·Q^T; kf shared across halves
        f32x4 st0[4] = {}, st1[4] = {};
        #pragma unroll
        for (int nt = 0; nt < 4; ++nt) {
            int n = nt * 16 + l15;      // key row in Ks
            #pragma unroll
            for (int kc = 0; kc < 2; ++kc) {
                int ch = (((kc * 4 + q4) ^ (n & 7)) * 8);
                bf16x8 kf = *(const bf16x8*)(&Ks[buf][n * 64 + ch]);
                st0[nt] = __builtin_amdgcn_mfma_f32_16x16x32_bf16(kf, qf[0][kc], st0[nt], 0, 0, 0);
                st1[nt] = __builtin_amdgcn_mfma_f32_16x16x32_bf16(kf, qf[1][kc], st1[nt], 0, 0, 0);
            }
        }

        if (kt == 2 * qt) {             // diagonal for half 0 (uniform branch)
            #pragma unroll
            for (int nt = 0; nt < 4; ++nt)
                #pragma unroll
                for (int r = 0; r < 4; ++r) {
                    int keyl = nt * 16 + q4 * 4 + r;
                    if (keyl > w * 16 + l15) st0[nt][r] = -1e30f;
                }
        }

        // P^T = 2^(S^T) packed to bf16x4 B-frags (k = q4*4+j), in registers
        bf16x4 pb0[4], pb1[4];
        #pragma unroll
        for (int nt = 0; nt < 4; ++nt)
            #pragma unroll
            for (int r = 0; r < 4; ++r) {
                pb0[nt][r] = (__bf16)__builtin_amdgcn_exp2f(st0[nt][r]);
                pb1[nt][r] = (__bf16)__builtin_amdgcn_exp2f(st1[nt][r]);
            }

        // O^T += V^T · P^T  (vf shared across halves); l += ones · P^T
        #pragma unroll
        for (int nt = 0; nt < 4; ++nt) {
            #pragma unroll
            for (int mt = 0; mt < 4; ++mt) {
                int row = mt * 16 + l15;                       // d row in Vs
                int ch = (nt * 2 + (q4 >> 1)) ^ (row & 7);
                bf16x4 vf = *(const bf16x4*)(&Vs[buf][row * 64 + ch * 8 + (q4 & 1) * 4]);
                o0[mt] = mfma16(vf, pb0[nt], o0[mt]);
                o1[mt] = mfma16(vf, pb1[nt], o1[mt]);
            }
            la0 = mfma16(ones4, pb0[nt], la0);
            la1 = mfma16(ones4, pb1[nt], la1);
        }
    }

    // ---- tail tile ktlast: half 0 fully masked; half 1 only ----------------
    {
        const int buf = ktlast % 3;
        __syncthreads();

        f32x4 st1[4] = {};
        #pragma unroll
        for (int nt = 0; nt < 4; ++nt) {
            int n = nt * 16 + l15;
            #pragma unroll
            for (int kc = 0; kc < 2; ++kc) {
                int ch = (((kc * 4 + q4) ^ (n & 7)) * 8);
                bf16x8 kf = *(const bf16x8*)(&Ks[buf][n * 64 + ch]);
                st1[nt] = __builtin_amdgcn_mfma_f32_16x16x32_bf16(kf, qf[1][kc], st1[nt], 0, 0, 0);
            }
        }
        bf16x4 pb1[4];
        #pragma unroll
        for (int nt = 0; nt < 4; ++nt)
            #pragma unroll
            for (int r = 0; r < 4; ++r) {
                int keyl = nt * 16 + q4 * 4 + r;
                float s = (keyl > w * 16 + l15) ? -1e30f : st1[nt][r];
                pb1[nt][r] = (__bf16)__builtin_amdgcn_exp2f(s);
            }
        #pragma unroll
        for (int nt = 0; nt < 4; ++nt) {
            #pragma unroll
            for (int mt = 0; mt < 4; ++mt) {
                int row = mt * 16 + l15;
                int ch = (nt * 2 + (q4 >> 1)) ^ (row & 7);
                bf16x4 vf = *(const bf16x4*)(&Vs[buf][row * 64 + ch * 8 + (q4 & 1) * 4]);
                o1[mt] = mfma16(vf, pb1[nt], o1[mt]);
            }
            la1 = mfma16(ones4, pb1[nt], la1);
        }
    }

    // epilogue: lane holds O^T[d = mt*16+q4*4+r][q=l15]; packed 8B stores
    float inv0 = 1.0f / la0[0], inv1 = 1.0f / la1[0];
    int row0 = qt * 128 + w * 16 + l15;
    int row1 = row0 + 64;
    #pragma unroll
    for (int mt = 0; mt < 4; ++mt) {
        union { __bf16 b[4]; ushort4 v; } p0, p1;
        #pragma unroll
        for (int r = 0; r < 4; ++r) {
            p0.b[r] = (__bf16)(o0[mt][r] * inv0);
            p1.b[r] = (__bf16)(o1[mt][r] * inv1);
        }
        int col = h * HDIM + mt * 16 + q4 * 4;
        *(ushort4*)(&outb[(base + row0) * (size_t)DMODEL + col]) = p0.v;
        *(ushort4*)(&outb[(base + row1) * (size_t)DMODEL + col]) = p1.v;
    }
}

// block = (bx, bh): processes Q-tiles qt = NT-1-bx and qt = bx (34 K-iters
// total for every block -> perfect load balance). gridDim.x = NT/2 = 8.
__global__ __launch_bounds__(256, 3) void attn_kernel(
    const u16* __restrict__ qkv, const u16* __restrict__ vt, u16* __restrict__ out)
{
    __shared__ __attribute__((aligned(16))) u16 Ks[3][64 * 64];
    __shared__ __attribute__((aligned(16))) u16 Vs[3][64 * 64];

    const int tid = threadIdx.x;
    const int w = tid >> 6, lane = tid & 63;
    const int bh = blockIdx.y;
    const int b = bh >> 4, h = bh & 15;
    const size_t base = (size_t)b * S_LEN;
    const int NT = (int)gridDim.x * 2;           // 16

    attn_pass(NT - 1 - (int)blockIdx.x, qkv, vt, (__bf16*)out, Ks, Vs, w, lane, bh, h, base);
    attn_pass((int)blockIdx.x,          qkv, vt, (__bf16*)out, Ks, Vs, w, lane, bh, h, base);
}

extern "C" void kernel_launch(void* const* d_in, const int* in_sizes, int n_in,
                              void* d_out, int out_size, void* d_ws, size_t ws_size,
                              hipStream_t stream) {
    const float* x      = (const float*)d_in[0];
    // d_in[1] = mask (causal tril) — implemented structurally, not read
    const float* w_attn = (const float*)d_in[2];
    const float* b_attn = (const float*)d_in[3];
    const float* w_proj = (const float*)d_in[4];
    const float* b_proj = (const float*)d_in[5];

    u16* xb   = (u16*)d_ws;                                   // 8192x1024 (dead after QKV GEMM)
    u16* wat  = xb  + (size_t)MTOT * DMODEL;                  // 3072x1024
    u16* wpt  = wat + (size_t)NQKV * DMODEL;                  // 1024x1024
    u16* qkv  = wpt + (size_t)DMODEL * DMODEL;                // 8192x3072
    u16* attn = qkv + (size_t)MTOT * NQKV;                    // 8192x1024
    u16* vt   = xb;                                           // Vt[64 bh][64 d][2048 s] aliases xb

    convert_x_kernel<<<(MTOT * DMODEL / 4 + 255) / 256, 256, 0, stream>>>(
        (const float4*)x, (ushort4*)xb, MTOT * DMODEL / 4);
    transpose_bf16_kernel<<<dim3(NQKV / 64, DMODEL / 64), 256, 0, stream>>>(w_attn, wat, DMODEL, NQKV);
    transpose_bf16_kernel<<<dim3(DMODEL / 64, DMODEL / 64), 256, 0, stream>>>(w_proj, wpt, DMODEL, DMODEL);

    gemm32<4, true><<<dim3((MTOT / 256) * (NQKV / 256)), 512, 0, stream>>>(
        xb, wat, b_attn, (void*)qkv, MTOT, NQKV, DMODEL);

    transpose_v_kernel<<<dim3(S_LEN / 64, 4 * NHEAD), 256, 0, stream>>>(qkv, vt);

    attn_kernel<<<dim3(S_LEN / 256, 4 * NHEAD), 256, 0, stream>>>(qkv, vt, attn);

    gemm32<2, false><<<dim3((MTOT / 256) * (DMODEL / 128)), 512, 0, stream>>>(
        attn, wpt, b_proj, d_out, MTOT, DMODEL, DMODEL);
}

// Round 5
// 273.700 us; speedup vs baseline: 1.0182x; 1.0001x over previous
//
#include <hip/hip_runtime.h>
#include <hip/hip_bf16.h>
#include <stdint.h>

// ---------------------------------------------------------------------------
// CausalSelfAttention: x(4,2048,1024) fp32 -> out fp32
// qkv = x@w_attn+b_attn; flash-attn causal (H=16,hd=64); out = attn@w_proj+b_proj
// R11: gemm16q — phases split by C-QUADRANT (m201), not by k-subtile.
//   R7-R10 all pinned at ~27% MfmaUtil because k-split phases accumulate into
//   the SAME acc regs -> phase p+1's first MFMA depends on phase p's result ->
//   after every barrier all waves stall on their own matrix-pipe drain.
//   Quadrant split: phase p computes acc[2p..2p+1][*] over full K=64 (16 MFMA,
//   disjoint acc per phase) -> p+1's MFMAs issue while p's drain; LDS reads
//   hide under the drain. 16x16x32 fragments (verified 0 bank conflicts; R10's
//   32x32 pattern re-introduced 4.7M). bfr (8 reads) in phase 0 only, held in
//   regs. Staging: A(t+1) halves p0/p1, B(t+2) p2/p3 into live parity (safe:
//   bfr retired by p0 MFMA waits + 2 barriers). Boundary = counted vmcnt,
//   never 0 in-loop. Swizzle + XCD A-panel mapping (FETCH 41MB) unchanged.
//   QKV: NF=4 (BN=256, grid 384); proj: NF=2 (BN=128, grid 256 = 1/CU exact).
// attn (R6): paired Q-tiles, triple-buffered K/V ring, exp2 softmax (unchanged).
// Workspace: xb 16MB (aliased by Vt after QKV GEMM) | wat 6MB | wpt 2MB |
//            qkv 48MB | attn 16MB  = 88 MB
// ---------------------------------------------------------------------------

typedef uint16_t u16;
typedef __bf16 bf16x8 __attribute__((ext_vector_type(8)));
typedef __bf16 bf16x4 __attribute__((ext_vector_type(4)));
typedef short s16x4 __attribute__((ext_vector_type(4)));
typedef float f32x4 __attribute__((ext_vector_type(4)));

#define S_LEN 2048
#define DMODEL 1024
#define NHEAD 16
#define HDIM 64
#define MTOT 8192   // B*S
#define NQKV 3072

__device__ __forceinline__ u16 f2bf(float f) {
    union { float f; uint32_t u; } v; v.f = f;
    uint32_t u = v.u;
    return (u16)((u + 0x7fffu + ((u >> 16) & 1u)) >> 16);  // RNE
}

__device__ __forceinline__ s16x4 bits4(bf16x4 v) {
    union { bf16x4 b; s16x4 s; } u; u.b = v; return u.s;
}

// D = A*B + C, 16x16x16 bf16 (A,B: 4 bf16/lane, k = q4*4+j)
__device__ __forceinline__ f32x4 mfma16(bf16x4 a, bf16x4 b, f32x4 c) {
    return __builtin_amdgcn_mfma_f32_16x16x16bf16_1k(bits4(a), bits4(b), c, 0, 0, 0);
}

__device__ __forceinline__ void async_load16(const void* g, void* l) {
    __builtin_amdgcn_global_load_lds(
        (__attribute__((address_space(1))) void*)g,
        (__attribute__((address_space(3))) void*)l,
        16, 0, 0);
}

// ---- prep: fp32 -> bf16 (vectorized) --------------------------------------
__global__ void convert_x_kernel(const float4* __restrict__ in, ushort4* __restrict__ out, int n4) {
    int i = blockIdx.x * 256 + threadIdx.x;
    if (i < n4) {
        float4 f = in[i];
        ushort4 o;
        o.x = f2bf(f.x); o.y = f2bf(f.y); o.z = f2bf(f.z); o.w = f2bf(f.w);
        out[i] = o;
    }
}

// ---- prep: transpose + convert: in (R x C) fp32 -> out (C x R) bf16 --------
__global__ void transpose_bf16_kernel(const float* __restrict__ in, u16* __restrict__ out, int R, int C) {
    __shared__ float tile[64][65];
    int r0 = blockIdx.y * 64, c0 = blockIdx.x * 64;
    #pragma unroll
    for (int i = 0; i < 16; ++i) {
        int idx = threadIdx.x + i * 256;
        int r = idx >> 6, c = idx & 63;
        tile[r][c] = in[(size_t)(r0 + r) * C + c0 + c];
    }
    __syncthreads();
    #pragma unroll
    for (int i = 0; i < 16; ++i) {
        int idx = threadIdx.x + i * 256;
        int c = idx >> 6, r = idx & 63;
        out[(size_t)(c0 + c) * R + r0 + r] = f2bf(tile[r][c]);
    }
}

// ---- V transpose: qkv V-section (token-major) -> Vt[bh][d][s] --------------
__global__ void transpose_v_kernel(const u16* __restrict__ qkv, u16* __restrict__ vt) {
    __shared__ u16 tile[64 * 66];
    const int tid = threadIdx.x;
    const int stile = blockIdx.x, bh = blockIdx.y;
    const int b = bh >> 4, h = bh & 15;
    const u16* src = qkv + ((size_t)b * S_LEN + stile * 64) * NQKV + 2 * DMODEL + h * HDIM;
    #pragma unroll
    for (int it = 0; it < 2; ++it) {
        int item = it * 256 + tid;
        int s = item >> 3, d0 = (item & 7) * 8;
        bf16x8 v = *(const bf16x8*)(src + (size_t)s * NQKV + d0);
        const u16* vu = (const u16*)&v;
        #pragma unroll
        for (int j = 0; j < 8; ++j) tile[(d0 + j) * 66 + s] = vu[j];
    }
    __syncthreads();
    #pragma unroll
    for (int it = 0; it < 2; ++it) {
        int item = it * 256 + tid;
        int d = item >> 3, s0 = (item & 7) * 8;
        union { u16 u[8]; uint4 v; } pk;
        #pragma unroll
        for (int j = 0; j < 8; ++j) pk.u[j] = tile[d * 66 + s0 + j];
        *(uint4*)(vt + ((size_t)bh * 64 + d) * S_LEN + stile * 64 + s0) = pk.v;
    }
}

// ---- GEMM16Q: C[M,N] = A[M,K] @ Bt[N,K]^T + bias, quadrant phases ----------
// BM=256, BN=NF*64, BK=64; 512 threads = 8 waves (wm=wave>>2 in M, wn=wave&3
// in N); per-wave output 128 x NF*16 (mf 0..7, nf 0..NF-1, 16x16x32 MFMA).
// LDS: A 4 half-slots [par][half] 128x64 (16KB, wave reads half wm only);
// B 2 slots [par] of BNx64. Chunk-XOR swizzle (chunk ^= row&7): linear LDS
// dest (global_load_lds) + inverse-swizzled global src + swizzled ds_read.
// Per K-tile 4 phases; phase p: {af reads for m-frags 2p,2p+1 (+ all NF*2 bfr
// reads in p0, held in regs all tile) | stage 1 half-tile | barrier |
// setprio(1) + 2*NF*2 MFMA into acc[2p..2p+1][*] (DISJOINT acc per phase ->
// no inter-phase MFMA deps; pipe drains overlap next phase's reads) |
// setprio(0) | barrier}. Staging: p0/p1 A(t+1) halves; p2/p3 B(t+2) into
// B[par] (safe: bfr retired by p0's MFMA waits, 2 barriers earlier).
// Boundary: vmcnt(NF) keeps B(t+2) in flight; never 0 in-loop.
// Mapping: xcd=bid&7 owns fixed 4-mb-row A panel (2MB, L2-resident), sweeps nb.
template<int NF, bool OUT_BF16>
__global__ __launch_bounds__(512, 2) void gemm16q(
    const u16* __restrict__ A, const u16* __restrict__ Bt,
    const float* __restrict__ bias, void* __restrict__ C,
    int M, int N, int K)
{
    constexpr int NBH = NF / 2;            // B half-tiles (128 rows) per K-tile
    constexpr int BSLOT = NF * 4096;       // u16 per B parity buffer (BN x 64)
    __shared__ __attribute__((aligned(16))) u16 sm[32768 + 2 * BSLOT];
    u16* const As = sm;                    // 4 x 8192 u16: slot (par*2+half)
    u16* const Bs = sm + 32768;            // 2 x BSLOT u16: slot par

    const int tid = threadIdx.x;
    const int wave = tid >> 6, lane = tid & 63;
    const int l15 = lane & 15, q4 = lane >> 4;
    const int wm = wave >> 2, wn = wave & 3;

    // XCD-resident A-panel mapping
    const int bid = (int)blockIdx.x;
    const int xcd = bid & 7;
    const int lx  = bid >> 3;
    const int MB  = M >> 8;                // 32
    const int PM  = MB >> 3;               // 4 rows per XCD panel
    const int nb  = lx / PM;
    const int mb  = xcd * PM + (lx - nb * PM);
    const int m0 = mb << 8, n0 = nb * NF * 64;

    const u16* Ag = A + (size_t)m0 * K;
    const u16* Bg = Bt + (size_t)n0 * K;

    // staging: per thread 2x16B per 128x64 half-tile; linear LDS dest,
    // inverse-swizzled global source
    const int srow = tid >> 3;
    const size_t goff0 = (size_t)srow * K + (size_t)(((tid & 7) ^ (srow & 7)) * 8);
    const size_t goff1 = goff0 + (size_t)64 * K;
    const int ldso = tid * 8;

    // swizzled ds_read chunk offsets (u16 units); frag row % 8 == l15 & 7
    const int ck0 = (q4 ^ (l15 & 7)) * 8;
    const int ck1 = ((4 + q4) ^ (l15 & 7)) * 8;
    const int rb0 = (wn * NF * 16 + l15) * 64;   // B row base (nf=0)

    f32x4 acc[8][NF] = {};
    const int T = K >> 6;

#define STAGE_A(t_, h_) do { \
    const u16* ga_ = Ag + (size_t)(h_) * 128 * K + (size_t)(t_) * 64; \
    u16* da_ = As + (((t_) & 1) * 2 + (h_)) * 8192; \
    async_load16(ga_ + goff0, da_ + ldso); \
    async_load16(ga_ + goff1, da_ + ldso + 4096); \
} while (0)

#define STAGE_B(t_, h_) do { \
    const u16* gb_ = Bg + (size_t)(h_) * 128 * K + (size_t)(t_) * 64; \
    u16* db_ = Bs + ((t_) & 1) * BSLOT + (h_) * 8192; \
    async_load16(gb_ + goff0, db_ + ldso); \
    async_load16(gb_ + goff1, db_ + ldso + 4096); \
} while (0)

#define LOAD_AF(P_) do { \
    af[0][0] = *(const bf16x8*)(Ah + ((2 * (P_)) * 16 + l15) * 64 + ck0); \
    af[0][1] = *(const bf16x8*)(Ah + ((2 * (P_)) * 16 + l15) * 64 + ck1); \
    af[1][0] = *(const bf16x8*)(Ah + ((2 * (P_) + 1) * 16 + l15) * 64 + ck0); \
    af[1][1] = *(const bf16x8*)(Ah + ((2 * (P_) + 1) * 16 + l15) * 64 + ck1); \
} while (0)

#define PHASE_MFMA(P_) do { \
    asm volatile("s_barrier" ::: "memory"); \
    __builtin_amdgcn_s_setprio(1); \
    _Pragma("unroll") \
    for (int i_ = 0; i_ < 2; ++i_) \
        _Pragma("unroll") \
        for (int nf_ = 0; nf_ < NF; ++nf_) \
            _Pragma("unroll") \
            for (int kk_ = 0; kk_ < 2; ++kk_) \
                acc[2 * (P_) + i_][nf_] = __builtin_amdgcn_mfma_f32_16x16x32_bf16( \
                    af[i_][kk_], bfr[nf_][kk_], acc[2 * (P_) + i_][nf_], 0, 0, 0); \
    __builtin_amdgcn_s_setprio(0); \
} while (0)

    // prologue: A(0) both halves + B(0) + B(1); keep B(1) in flight
    STAGE_A(0, 0); STAGE_A(0, 1);
    STAGE_B(0, 0); if constexpr (NBH == 2) STAGE_B(0, 1);
    if (T > 1) {
        STAGE_B(1, 0); if constexpr (NBH == 2) STAGE_B(1, 1);
        if constexpr (NBH == 2) asm volatile("s_waitcnt vmcnt(4)" ::: "memory");
        else                    asm volatile("s_waitcnt vmcnt(2)" ::: "memory");
    } else {
        asm volatile("s_waitcnt vmcnt(0)" ::: "memory");
    }
    asm volatile("s_barrier" ::: "memory");

    for (int t = 0; t < T; ++t) {
        const int par = t & 1;
        const u16* Ah = As + (par * 2 + wm) * 8192;   // this wave's A half
        const u16* Bl = Bs + par * BSLOT;

        bf16x8 af[2][2], bfr[NF][2];

        // ---- phase 0: ALL bfr (held all tile) + af m-frags 0,1;
        //               stage A(t+1).h0 --------------------------------------
        #pragma unroll
        for (int nf = 0; nf < NF; ++nf) {
            bfr[nf][0] = *(const bf16x8*)(Bl + rb0 + nf * (16 * 64) + ck0);
            bfr[nf][1] = *(const bf16x8*)(Bl + rb0 + nf * (16 * 64) + ck1);
        }
        LOAD_AF(0);
        if (t + 1 < T) STAGE_A(t + 1, 0);
        if constexpr (NF == 4)    // pace the 12-read burst (m201 hint)
            asm volatile("s_waitcnt lgkmcnt(8)" ::: "memory");
        PHASE_MFMA(0);
        asm volatile("s_barrier" ::: "memory");

        // ---- phase 1: af m-frags 2,3; stage A(t+1).h1 ----------------------
        LOAD_AF(1);
        if (t + 1 < T) STAGE_A(t + 1, 1);
        PHASE_MFMA(1);
        asm volatile("s_barrier" ::: "memory");

        // ---- phase 2: af m-frags 4,5; stage B(t+2).h0 into B[par] ----------
        LOAD_AF(2);
        if (t + 2 < T) STAGE_B(t + 2, 0);
        PHASE_MFMA(2);
        asm volatile("s_barrier" ::: "memory");

        // ---- phase 3: af m-frags 6,7; stage B(t+2).h1 ----------------------
        LOAD_AF(3);
        if constexpr (NBH == 2) { if (t + 2 < T) STAGE_B(t + 2, 1); }
        PHASE_MFMA(3);
        // boundary: A(t+1)+B(t+1) complete; B(t+2) loads stay in flight
        if (t + 1 < T) {
            if (t + 2 < T) {
                if constexpr (NBH == 2) asm volatile("s_waitcnt vmcnt(4)" ::: "memory");
                else                    asm volatile("s_waitcnt vmcnt(2)" ::: "memory");
            } else {
                asm volatile("s_waitcnt vmcnt(0)" ::: "memory");
            }
            asm volatile("s_barrier" ::: "memory");
        }
    }

#undef STAGE_A
#undef STAGE_B
#undef LOAD_AF
#undef PHASE_MFMA

    // epilogue: C/D col=l15, row=q4*4+r
    #pragma unroll
    for (int mf = 0; mf < 8; ++mf) {
        const int row = m0 + wm * 128 + mf * 16 + q4 * 4;
        #pragma unroll
        for (int nf = 0; nf < NF; ++nf) {
            const int col = n0 + wn * NF * 16 + nf * 16 + l15;
            const float bv = bias[col];
            #pragma unroll
            for (int r = 0; r < 4; ++r) {
                float v = acc[mf][nf][r] + bv;
                if (OUT_BF16) ((u16*)C)[(size_t)(row + r) * N + col] = f2bf(v);
                else          ((float*)C)[(size_t)(row + r) * N + col] = v;
            }
        }
    }
}

// ---- flash attention R6 ----------------------------------------------------
// One Q-tile pass (128 q-rows at qt). Triple-buffered K/V, prefetch-2,
// S^T = K·Q^T -> exp2 -> P^T B-frags in registers -> O^T = V^T·P^T.
__device__ __forceinline__ void stage_tiles(
    const u16* __restrict__ qkv, const u16* __restrict__ vt,
    size_t base, int bh, int h, int w, int srow8, int schunk,
    int kt, u16* __restrict__ KsB, u16* __restrict__ VsB)
{
    #pragma unroll
    for (int q = 0; q < 2; ++q) {
        int rloc = w * 16 + q * 8 + srow8;
        int sc = ((schunk ^ (rloc & 7)) * 8);
        async_load16(qkv + (base + (size_t)kt * 64 + rloc) * (size_t)NQKV + DMODEL + h * HDIM + sc,
                     KsB + (w * 16 + q * 8) * 64);
        async_load16(vt + ((size_t)bh * 64 + rloc) * S_LEN + kt * 64 + sc,
                     VsB + (w * 16 + q * 8) * 64);
    }
}

__device__ __forceinline__ void attn_pass(
    int qt, const u16* __restrict__ qkv, const u16* __restrict__ vt,
    __bf16* __restrict__ outb, u16 (*Ks)[64 * 64], u16 (*Vs)[64 * 64],
    int w, int lane, int bh, int h, size_t base)
{
    const int l15 = lane & 15, q4 = lane >> 4;
    const int srow8 = lane >> 3, schunk = lane & 7;

    // Q fragments for both halves ([n=q=l15][k=d=q4*8+j]); scale folds
    // 1/sqrt(64) * log2(e) so P = 2^(K·Q^T) == e^(K·Q^T/8).
    const float QSCALE = 0.125f * 1.44269504f;
    bf16x8 qf[2][2];
    #pragma unroll
    for (int mh = 0; mh < 2; ++mh) {
        int qrow = qt * 128 + mh * 64 + w * 16 + l15;
        #pragma unroll
        for (int kc = 0; kc < 2; ++kc) {
            bf16x8 raw = *(const bf16x8*)(qkv + (base + qrow) * (size_t)NQKV + h * HDIM + kc * 32 + q4 * 8);
            bf16x8 sc;
            #pragma unroll
            for (int j = 0; j < 8; ++j) sc[j] = (__bf16)((float)raw[j] * QSCALE);
            qf[mh][kc] = sc;
        }
    }

    bf16x4 ones4;
    #pragma unroll
    for (int j = 0; j < 4; ++j) ones4[j] = (__bf16)1.0f;

    f32x4 o0[4] = {}, o1[4] = {};   // O^T: [d-tile mt][q=l15], rows d=q4*4+r
    f32x4 la0 = {}, la1 = {};       // l[q=l15]

    const int ktlast = 2 * qt + 1;  // tail tile (half-0 fully masked)

    __syncthreads();                // protect LDS reuse across passes
    stage_tiles(qkv, vt, base, bh, h, w, srow8, schunk, 0, Ks[0], Vs[0]);
    if (ktlast >= 1)
        stage_tiles(qkv, vt, base, bh, h, w, srow8, schunk, 1, Ks[1], Vs[1]);

    for (int kt = 0; kt <= 2 * qt; ++kt) {
        const int buf = kt % 3;
        __syncthreads();            // kt,kt+1 staged; reads of buf (kt+2)%3 done
        int pf = kt + 2;
        if (pf <= ktlast)
            stage_tiles(qkv, vt, base, bh, h, w, srow8, schunk, pf, Ks[pf % 3], Vs[pf % 3]);

        // S^T = K·Q^T; kf shared across halves
        f32x4 st0[4] = {}, st1[4] = {};
        #pragma unroll
        for (int nt = 0; nt < 4; ++nt) {
            int n = nt * 16 + l15;      // key row in Ks
            #pragma unroll
            for (int kc = 0; kc < 2; ++kc) {
                int ch = (((kc * 4 + q4) ^ (n & 7)) * 8);
                bf16x8 kf = *(const bf16x8*)(&Ks[buf][n * 64 + ch]);
                st0[nt] = __builtin_amdgcn_mfma_f32_16x16x32_bf16(kf, qf[0][kc], st0[nt], 0, 0, 0);
                st1[nt] = __builtin_amdgcn_mfma_f32_16x16x32_bf16(kf, qf[1][kc], st1[nt], 0, 0, 0);
            }
        }

        if (kt == 2 * qt) {             // diagonal for half 0 (uniform branch)
            #pragma unroll
            for (int nt = 0; nt < 4; ++nt)
                #pragma unroll
                for (int r = 0; r < 4; ++r) {
                    int keyl = nt * 16 + q4 * 4 + r;
                    if (keyl > w * 16 + l15) st0[nt][r] = -1e30f;
                }
        }

        // P^T = 2^(S^T) packed to bf16x4 B-frags (k = q4*4+j), in registers
        bf16x4 pb0[4], pb1[4];
        #pragma unroll
        for (int nt = 0; nt < 4; ++nt)
            #pragma unroll
            for (int r = 0; r < 4; ++r) {
                pb0[nt][r] = (__bf16)__builtin_amdgcn_exp2f(st0[nt][r]);
                pb1[nt][r] = (__bf16)__builtin_amdgcn_exp2f(st1[nt][r]);
            }

        // O^T += V^T · P^T  (vf shared across halves); l += ones · P^T
        #pragma unroll
        for (int nt = 0; nt < 4; ++nt) {
            #pragma unroll
            for (int mt = 0; mt < 4; ++mt) {
                int row = mt * 16 + l15;                       // d row in Vs
                int ch = (nt * 2 + (q4 >> 1)) ^ (row & 7);
                bf16x4 vf = *(const bf16x4*)(&Vs[buf][row * 64 + ch * 8 + (q4 & 1) * 4]);
                o0[mt] = mfma16(vf, pb0[nt], o0[mt]);
                o1[mt] = mfma16(vf, pb1[nt], o1[mt]);
            }
            la0 = mfma16(ones4, pb0[nt], la0);
            la1 = mfma16(ones4, pb1[nt], la1);
        }
    }

    // ---- tail tile ktlast: half 0 fully masked; half 1 only ----------------
    {
        const int buf = ktlast % 3;
        __syncthreads();

        f32x4 st1[4] = {};
        #pragma unroll
        for (int nt = 0; nt < 4; ++nt) {
            int n = nt * 16 + l15;
            #pragma unroll
            for (int kc = 0; kc < 2; ++kc) {
                int ch = (((kc * 4 + q4) ^ (n & 7)) * 8);
                bf16x8 kf = *(const bf16x8*)(&Ks[buf][n * 64 + ch]);
                st1[nt] = __builtin_amdgcn_mfma_f32_16x16x32_bf16(kf, qf[1][kc], st1[nt], 0, 0, 0);
            }
        }
        bf16x4 pb1[4];
        #pragma unroll
        for (int nt = 0; nt < 4; ++nt)
            #pragma unroll
            for (int r = 0; r < 4; ++r) {
                int keyl = nt * 16 + q4 * 4 + r;
                float s = (keyl > w * 16 + l15) ? -1e30f : st1[nt][r];
                pb1[nt][r] = (__bf16)__builtin_amdgcn_exp2f(s);
            }
        #pragma unroll
        for (int nt = 0; nt < 4; ++nt) {
            #pragma unroll
            for (int mt = 0; mt < 4; ++mt) {
                int row = mt * 16 + l15;
                int ch = (nt * 2 + (q4 >> 1)) ^ (row & 7);
                bf16x4 vf = *(const bf16x4*)(&Vs[buf][row * 64 + ch * 8 + (q4 & 1) * 4]);
                o1[mt] = mfma16(vf, pb1[nt], o1[mt]);
            }
            la1 = mfma16(ones4, pb1[nt], la1);
        }
    }

    // epilogue: lane holds O^T[d = mt*16+q4*4+r][q=l15]; packed 8B stores
    float inv0 = 1.0f / la0[0], inv1 = 1.0f / la1[0];
    int row0 = qt * 128 + w * 16 + l15;
    int row1 = row0 + 64;
    #pragma unroll
    for (int mt = 0; mt < 4; ++mt) {
        union { __bf16 b[4]; ushort4 v; } p0, p1;
        #pragma unroll
        for (int r = 0; r < 4; ++r) {
            p0.b[r] = (__bf16)(o0[mt][r] * inv0);
            p1.b[r] = (__bf16)(o1[mt][r] * inv1);
        }
        int col = h * HDIM + mt * 16 + q4 * 4;
        *(ushort4*)(&outb[(base + row0) * (size_t)DMODEL + col]) = p0.v;
        *(ushort4*)(&outb[(base + row1) * (size_t)DMODEL + col]) = p1.v;
    }
}

// block = (bx, bh): processes Q-tiles qt = NT-1-bx and qt = bx (34 K-iters
// total for every block -> perfect load balance). gridDim.x = NT/2 = 8.
__global__ __launch_bounds__(256, 3) void attn_kernel(
    const u16* __restrict__ qkv, const u16* __restrict__ vt, u16* __restrict__ out)
{
    __shared__ __attribute__((aligned(16))) u16 Ks[3][64 * 64];
    __shared__ __attribute__((aligned(16))) u16 Vs[3][64 * 64];

    const int tid = threadIdx.x;
    const int w = tid >> 6, lane = tid & 63;
    const int bh = blockIdx.y;
    const int b = bh >> 4, h = bh & 15;
    const size_t base = (size_t)b * S_LEN;
    const int NT = (int)gridDim.x * 2;           // 16

    attn_pass(NT - 1 - (int)blockIdx.x, qkv, vt, (__bf16*)out, Ks, Vs, w, lane, bh, h, base);
    attn_pass((int)blockIdx.x,          qkv, vt, (__bf16*)out, Ks, Vs, w, lane, bh, h, base);
}

extern "C" void kernel_launch(void* const* d_in, const int* in_sizes, int n_in,
                              void* d_out, int out_size, void* d_ws, size_t ws_size,
                              hipStream_t stream) {
    const float* x      = (const float*)d_in[0];
    // d_in[1] = mask (causal tril) — implemented structurally, not read
    const float* w_attn = (const float*)d_in[2];
    const float* b_attn = (const float*)d_in[3];
    const float* w_proj = (const float*)d_in[4];
    const float* b_proj = (const float*)d_in[5];

    u16* xb   = (u16*)d_ws;                                   // 8192x1024 (dead after QKV GEMM)
    u16* wat  = xb  + (size_t)MTOT * DMODEL;                  // 3072x1024
    u16* wpt  = wat + (size_t)NQKV * DMODEL;                  // 1024x1024
    u16* qkv  = wpt + (size_t)DMODEL * DMODEL;                // 8192x3072
    u16* attn = qkv + (size_t)MTOT * NQKV;                    // 8192x1024
    u16* vt   = xb;                                           // Vt[64 bh][64 d][2048 s] aliases xb

    convert_x_kernel<<<(MTOT * DMODEL / 4 + 255) / 256, 256, 0, stream>>>(
        (const float4*)x, (ushort4*)xb, MTOT * DMODEL / 4);
    transpose_bf16_kernel<<<dim3(NQKV / 64, DMODEL / 64), 256, 0, stream>>>(w_attn, wat, DMODEL, NQKV);
    transpose_bf16_kernel<<<dim3(DMODEL / 64, DMODEL / 64), 256, 0, stream>>>(w_proj, wpt, DMODEL, DMODEL);

    gemm16q<4, true><<<dim3((MTOT / 256) * (NQKV / 256)), 512, 0, stream>>>(
        xb, wat, b_attn, (void*)qkv, MTOT, NQKV, DMODEL);

    transpose_v_kernel<<<dim3(S_LEN / 64, 4 * NHEAD), 256, 0, stream>>>(qkv, vt);

    attn_kernel<<<dim3(S_LEN / 256, 4 * NHEAD), 256, 0, stream>>>(qkv, vt, attn);

    gemm16q<2, false><<<dim3((MTOT / 256) * (DMODEL / 128)), 512, 0, stream>>>(
        attn, wpt, b_proj, d_out, MTOT, DMODEL, DMODEL);
}

// Round 6
// 269.998 us; speedup vs baseline: 1.0321x; 1.0137x over previous
//
#include <hip/hip_runtime.h>
#include <hip/hip_bf16.h>
#include <stdint.h>

// ---------------------------------------------------------------------------
// CausalSelfAttention: x(4,2048,1024) fp32 -> out fp32
// qkv = x@w_attn+b_attn; flash-attn causal (H=16,hd=64); out = attn@w_proj+b_proj
// R12: barrier mechanics fixed. R7-R11 all pinned at 27% MfmaUtil because the
//   barriers were inline-asm s_barrier with a "memory" clobber: LLVM's
//   waitcnt pass conservatively drains ALL counters (vmcnt(0) lgkmcnt(0))
//   before such asm -> every barrier became a full __syncthreads-style drain,
//   nullifying the counted-vmcnt pipeline in every structure variant.
//   Fix (m201 idiom, verbatim): __builtin_amdgcn_s_barrier() intrinsic for
//   barriers (no forced drain) + clobber-free "s_waitcnt vmcnt(N)" asm +
//   __builtin_amdgcn_sched_barrier(0) to pin order (rule #18).
//   Structure otherwise identical to R11: quadrant phases (disjoint acc per
//   phase), 16x16x32 frags (0 bank conflicts), chunk-XOR swizzle both-sides,
//   XCD A-panel mapping (FETCH 41MB), A(t+1) staged p0/p1, B(t+2) p2/p3,
//   boundary vmcnt(4)/vmcnt(2). QKV NF=4 (grid 384), proj NF=2 (grid 256).
// attn (R6): paired Q-tiles, triple-buffered K/V ring, exp2 softmax (unchanged).
// Workspace: xb 16MB (aliased by Vt after QKV GEMM) | wat 6MB | wpt 2MB |
//            qkv 48MB | attn 16MB  = 88 MB
// ---------------------------------------------------------------------------

typedef uint16_t u16;
typedef __bf16 bf16x8 __attribute__((ext_vector_type(8)));
typedef __bf16 bf16x4 __attribute__((ext_vector_type(4)));
typedef short s16x4 __attribute__((ext_vector_type(4)));
typedef float f32x4 __attribute__((ext_vector_type(4)));

#define S_LEN 2048
#define DMODEL 1024
#define NHEAD 16
#define HDIM 64
#define MTOT 8192   // B*S
#define NQKV 3072

__device__ __forceinline__ u16 f2bf(float f) {
    union { float f; uint32_t u; } v; v.f = f;
    uint32_t u = v.u;
    return (u16)((u + 0x7fffu + ((u >> 16) & 1u)) >> 16);  // RNE
}

__device__ __forceinline__ s16x4 bits4(bf16x4 v) {
    union { bf16x4 b; s16x4 s; } u; u.b = v; return u.s;
}

// D = A*B + C, 16x16x16 bf16 (A,B: 4 bf16/lane, k = q4*4+j)
__device__ __forceinline__ f32x4 mfma16(bf16x4 a, bf16x4 b, f32x4 c) {
    return __builtin_amdgcn_mfma_f32_16x16x16bf16_1k(bits4(a), bits4(b), c, 0, 0, 0);
}

__device__ __forceinline__ void async_load16(const void* g, void* l) {
    __builtin_amdgcn_global_load_lds(
        (__attribute__((address_space(1))) void*)g,
        (__attribute__((address_space(3))) void*)l,
        16, 0, 0);
}

// ---- prep: fp32 -> bf16 (vectorized) --------------------------------------
__global__ void convert_x_kernel(const float4* __restrict__ in, ushort4* __restrict__ out, int n4) {
    int i = blockIdx.x * 256 + threadIdx.x;
    if (i < n4) {
        float4 f = in[i];
        ushort4 o;
        o.x = f2bf(f.x); o.y = f2bf(f.y); o.z = f2bf(f.z); o.w = f2bf(f.w);
        out[i] = o;
    }
}

// ---- prep: transpose + convert: in (R x C) fp32 -> out (C x R) bf16 --------
__global__ void transpose_bf16_kernel(const float* __restrict__ in, u16* __restrict__ out, int R, int C) {
    __shared__ float tile[64][65];
    int r0 = blockIdx.y * 64, c0 = blockIdx.x * 64;
    #pragma unroll
    for (int i = 0; i < 16; ++i) {
        int idx = threadIdx.x + i * 256;
        int r = idx >> 6, c = idx & 63;
        tile[r][c] = in[(size_t)(r0 + r) * C + c0 + c];
    }
    __syncthreads();
    #pragma unroll
    for (int i = 0; i < 16; ++i) {
        int idx = threadIdx.x + i * 256;
        int c = idx >> 6, r = idx & 63;
        out[(size_t)(c0 + c) * R + r0 + r] = f2bf(tile[r][c]);
    }
}

// ---- V transpose: qkv V-section (token-major) -> Vt[bh][d][s] --------------
__global__ void transpose_v_kernel(const u16* __restrict__ qkv, u16* __restrict__ vt) {
    __shared__ u16 tile[64 * 66];
    const int tid = threadIdx.x;
    const int stile = blockIdx.x, bh = blockIdx.y;
    const int b = bh >> 4, h = bh & 15;
    const u16* src = qkv + ((size_t)b * S_LEN + stile * 64) * NQKV + 2 * DMODEL + h * HDIM;
    #pragma unroll
    for (int it = 0; it < 2; ++it) {
        int item = it * 256 + tid;
        int s = item >> 3, d0 = (item & 7) * 8;
        bf16x8 v = *(const bf16x8*)(src + (size_t)s * NQKV + d0);
        const u16* vu = (const u16*)&v;
        #pragma unroll
        for (int j = 0; j < 8; ++j) tile[(d0 + j) * 66 + s] = vu[j];
    }
    __syncthreads();
    #pragma unroll
    for (int it = 0; it < 2; ++it) {
        int item = it * 256 + tid;
        int d = item >> 3, s0 = (item & 7) * 8;
        union { u16 u[8]; uint4 v; } pk;
        #pragma unroll
        for (int j = 0; j < 8; ++j) pk.u[j] = tile[d * 66 + s0 + j];
        *(uint4*)(vt + ((size_t)bh * 64 + d) * S_LEN + stile * 64 + s0) = pk.v;
    }
}

// ---- GEMM16Q: C[M,N] = A[M,K] @ Bt[N,K]^T + bias, quadrant phases ----------
// BM=256, BN=NF*64, BK=64; 512 threads = 8 waves (wm=wave>>2 in M, wn=wave&3
// in N); per-wave output 128 x NF*16 (mf 0..7, nf 0..NF-1, 16x16x32 MFMA).
// LDS: A 4 half-slots [par][half] 128x64 (16KB, wave reads half wm only);
// B 2 slots [par] of BNx64. Chunk-XOR swizzle (chunk ^= row&7): linear LDS
// dest (global_load_lds) + inverse-swizzled global src + swizzled ds_read.
// Per K-tile 4 phases; phase p: {af reads for m-frags 2p,2p+1 (+ all NF*2 bfr
// reads in p0, held in regs all tile) | stage 1 half-tile | INTRINSIC barrier
// (no waitcnt drain!) | setprio(1) + 2*NF*2 MFMA into acc[2p..2p+1][*]
// (disjoint acc per phase) | setprio(0) | barrier}. Staging: p0/p1 A(t+1)
// halves; p2/p3 B(t+2) into B[par] (safe: bfr retired by p0's MFMA waits).
// Boundary: clobber-free vmcnt(NF) + sched_barrier(0); never 0 in-loop.
// Mapping: xcd=bid&7 owns fixed 4-mb-row A panel (2MB, L2-resident), sweeps nb.
template<int NF, bool OUT_BF16>
__global__ __launch_bounds__(512, 2) void gemm16q(
    const u16* __restrict__ A, const u16* __restrict__ Bt,
    const float* __restrict__ bias, void* __restrict__ C,
    int M, int N, int K)
{
    constexpr int NBH = NF / 2;            // B half-tiles (128 rows) per K-tile
    constexpr int BSLOT = NF * 4096;       // u16 per B parity buffer (BN x 64)
    __shared__ __attribute__((aligned(16))) u16 sm[32768 + 2 * BSLOT];
    u16* const As = sm;                    // 4 x 8192 u16: slot (par*2+half)
    u16* const Bs = sm + 32768;            // 2 x BSLOT u16: slot par

    const int tid = threadIdx.x;
    const int wave = tid >> 6, lane = tid & 63;
    const int l15 = lane & 15, q4 = lane >> 4;
    const int wm = wave >> 2, wn = wave & 3;

    // XCD-resident A-panel mapping
    const int bid = (int)blockIdx.x;
    const int xcd = bid & 7;
    const int lx  = bid >> 3;
    const int MB  = M >> 8;                // 32
    const int PM  = MB >> 3;               // 4 rows per XCD panel
    const int nb  = lx / PM;
    const int mb  = xcd * PM + (lx - nb * PM);
    const int m0 = mb << 8, n0 = nb * NF * 64;

    const u16* Ag = A + (size_t)m0 * K;
    const u16* Bg = Bt + (size_t)n0 * K;

    // staging: per thread 2x16B per 128x64 half-tile; linear LDS dest,
    // inverse-swizzled global source
    const int srow = tid >> 3;
    const size_t goff0 = (size_t)srow * K + (size_t)(((tid & 7) ^ (srow & 7)) * 8);
    const size_t goff1 = goff0 + (size_t)64 * K;
    const int ldso = tid * 8;

    // swizzled ds_read chunk offsets (u16 units); frag row % 8 == l15 & 7
    const int ck0 = (q4 ^ (l15 & 7)) * 8;
    const int ck1 = ((4 + q4) ^ (l15 & 7)) * 8;
    const int rb0 = (wn * NF * 16 + l15) * 64;   // B row base (nf=0)

    f32x4 acc[8][NF] = {};
    const int T = K >> 6;

#define STAGE_A(t_, h_) do { \
    const u16* ga_ = Ag + (size_t)(h_) * 128 * K + (size_t)(t_) * 64; \
    u16* da_ = As + (((t_) & 1) * 2 + (h_)) * 8192; \
    async_load16(ga_ + goff0, da_ + ldso); \
    async_load16(ga_ + goff1, da_ + ldso + 4096); \
} while (0)

#define STAGE_B(t_, h_) do { \
    const u16* gb_ = Bg + (size_t)(h_) * 128 * K + (size_t)(t_) * 64; \
    u16* db_ = Bs + ((t_) & 1) * BSLOT + (h_) * 8192; \
    async_load16(gb_ + goff0, db_ + ldso); \
    async_load16(gb_ + goff1, db_ + ldso + 4096); \
} while (0)

#define LOAD_AF(P_) do { \
    af[0][0] = *(const bf16x8*)(Ah + ((2 * (P_)) * 16 + l15) * 64 + ck0); \
    af[0][1] = *(const bf16x8*)(Ah + ((2 * (P_)) * 16 + l15) * 64 + ck1); \
    af[1][0] = *(const bf16x8*)(Ah + ((2 * (P_) + 1) * 16 + l15) * 64 + ck0); \
    af[1][1] = *(const bf16x8*)(Ah + ((2 * (P_) + 1) * 16 + l15) * 64 + ck1); \
} while (0)

#define PHASE_MFMA(P_) do { \
    __builtin_amdgcn_s_barrier(); \
    __builtin_amdgcn_s_setprio(1); \
    _Pragma("unroll") \
    for (int i_ = 0; i_ < 2; ++i_) \
        _Pragma("unroll") \
        for (int nf_ = 0; nf_ < NF; ++nf_) \
            _Pragma("unroll") \
            for (int kk_ = 0; kk_ < 2; ++kk_) \
                acc[2 * (P_) + i_][nf_] = __builtin_amdgcn_mfma_f32_16x16x32_bf16( \
                    af[i_][kk_], bfr[nf_][kk_], acc[2 * (P_) + i_][nf_], 0, 0, 0); \
    __builtin_amdgcn_s_setprio(0); \
} while (0)

    // prologue: A(0) both halves + B(0) + B(1); keep B(1) in flight
    STAGE_A(0, 0); STAGE_A(0, 1);
    STAGE_B(0, 0); if constexpr (NBH == 2) STAGE_B(0, 1);
    if (T > 1) {
        STAGE_B(1, 0); if constexpr (NBH == 2) STAGE_B(1, 1);
        if constexpr (NBH == 2) asm volatile("s_waitcnt vmcnt(4)");
        else                    asm volatile("s_waitcnt vmcnt(2)");
    } else {
        asm volatile("s_waitcnt vmcnt(0)");
    }
    __builtin_amdgcn_sched_barrier(0);
    __builtin_amdgcn_s_barrier();

    for (int t = 0; t < T; ++t) {
        const int par = t & 1;
        const u16* Ah = As + (par * 2 + wm) * 8192;   // this wave's A half
        const u16* Bl = Bs + par * BSLOT;

        bf16x8 af[2][2], bfr[NF][2];

        // ---- phase 0: ALL bfr (held all tile) + af m-frags 0,1;
        //               stage A(t+1).h0 --------------------------------------
        #pragma unroll
        for (int nf = 0; nf < NF; ++nf) {
            bfr[nf][0] = *(const bf16x8*)(Bl + rb0 + nf * (16 * 64) + ck0);
            bfr[nf][1] = *(const bf16x8*)(Bl + rb0 + nf * (16 * 64) + ck1);
        }
        LOAD_AF(0);
        if (t + 1 < T) STAGE_A(t + 1, 0);
        PHASE_MFMA(0);
        __builtin_amdgcn_s_barrier();

        // ---- phase 1: af m-frags 2,3; stage A(t+1).h1 ----------------------
        LOAD_AF(1);
        if (t + 1 < T) STAGE_A(t + 1, 1);
        PHASE_MFMA(1);
        __builtin_amdgcn_s_barrier();

        // ---- phase 2: af m-frags 4,5; stage B(t+2).h0 into B[par] ----------
        LOAD_AF(2);
        if (t + 2 < T) STAGE_B(t + 2, 0);
        PHASE_MFMA(2);
        __builtin_amdgcn_s_barrier();

        // ---- phase 3: af m-frags 6,7; stage B(t+2).h1 ----------------------
        LOAD_AF(3);
        if constexpr (NBH == 2) { if (t + 2 < T) STAGE_B(t + 2, 1); }
        PHASE_MFMA(3);
        // boundary: A(t+1)+B(t+1) complete; B(t+2) loads stay in flight
        if (t + 1 < T) {
            if (t + 2 < T) {
                if constexpr (NBH == 2) asm volatile("s_waitcnt vmcnt(4)");
                else                    asm volatile("s_waitcnt vmcnt(2)");
            } else {
                asm volatile("s_waitcnt vmcnt(0)");
            }
            __builtin_amdgcn_sched_barrier(0);
            __builtin_amdgcn_s_barrier();
        }
    }

#undef STAGE_A
#undef STAGE_B
#undef LOAD_AF
#undef PHASE_MFMA

    // epilogue: C/D col=l15, row=q4*4+r
    #pragma unroll
    for (int mf = 0; mf < 8; ++mf) {
        const int row = m0 + wm * 128 + mf * 16 + q4 * 4;
        #pragma unroll
        for (int nf = 0; nf < NF; ++nf) {
            const int col = n0 + wn * NF * 16 + nf * 16 + l15;
            const float bv = bias[col];
            #pragma unroll
            for (int r = 0; r < 4; ++r) {
                float v = acc[mf][nf][r] + bv;
                if (OUT_BF16) ((u16*)C)[(size_t)(row + r) * N + col] = f2bf(v);
                else          ((float*)C)[(size_t)(row + r) * N + col] = v;
            }
        }
    }
}

// ---- flash attention R6 ----------------------------------------------------
// One Q-tile pass (128 q-rows at qt). Triple-buffered K/V, prefetch-2,
// S^T = K·Q^T -> exp2 -> P^T B-frags in registers -> O^T = V^T·P^T.
__device__ __forceinline__ void stage_tiles(
    const u16* __restrict__ qkv, const u16* __restrict__ vt,
    size_t base, int bh, int h, int w, int srow8, int schunk,
    int kt, u16* __restrict__ KsB, u16* __restrict__ VsB)
{
    #pragma unroll
    for (int q = 0; q < 2; ++q) {
        int rloc = w * 16 + q * 8 + srow8;
        int sc = ((schunk ^ (rloc & 7)) * 8);
        async_load16(qkv + (base + (size_t)kt * 64 + rloc) * (size_t)NQKV + DMODEL + h * HDIM + sc,
                     KsB + (w * 16 + q * 8) * 64);
        async_load16(vt + ((size_t)bh * 64 + rloc) * S_LEN + kt * 64 + sc,
                     VsB + (w * 16 + q * 8) * 64);
    }
}

__device__ __forceinline__ void attn_pass(
    int qt, const u16* __restrict__ qkv, const u16* __restrict__ vt,
    __bf16* __restrict__ outb, u16 (*Ks)[64 * 64], u16 (*Vs)[64 * 64],
    int w, int lane, int bh, int h, size_t base)
{
    const int l15 = lane & 15, q4 = lane >> 4;
    const int srow8 = lane >> 3, schunk = lane & 7;

    // Q fragments for both halves ([n=q=l15][k=d=q4*8+j]); scale folds
    // 1/sqrt(64) * log2(e) so P = 2^(K·Q^T) == e^(K·Q^T/8).
    const float QSCALE = 0.125f * 1.44269504f;
    bf16x8 qf[2][2];
    #pragma unroll
    for (int mh = 0; mh < 2; ++mh) {
        int qrow = qt * 128 + mh * 64 + w * 16 + l15;
        #pragma unroll
        for (int kc = 0; kc < 2; ++kc) {
            bf16x8 raw = *(const bf16x8*)(qkv + (base + qrow) * (size_t)NQKV + h * HDIM + kc * 32 + q4 * 8);
            bf16x8 sc;
            #pragma unroll
            for (int j = 0; j < 8; ++j) sc[j] = (__bf16)((float)raw[j] * QSCALE);
            qf[mh][kc] = sc;
        }
    }

    bf16x4 ones4;
    #pragma unroll
    for (int j = 0; j < 4; ++j) ones4[j] = (__bf16)1.0f;

    f32x4 o0[4] = {}, o1[4] = {};   // O^T: [d-tile mt][q=l15], rows d=q4*4+r
    f32x4 la0 = {}, la1 = {};       // l[q=l15]

    const int ktlast = 2 * qt + 1;  // tail tile (half-0 fully masked)

    __syncthreads();                // protect LDS reuse across passes
    stage_tiles(qkv, vt, base, bh, h, w, srow8, schunk, 0, Ks[0], Vs[0]);
    if (ktlast >= 1)
        stage_tiles(qkv, vt, base, bh, h, w, srow8, schunk, 1, Ks[1], Vs[1]);

    for (int kt = 0; kt <= 2 * qt; ++kt) {
        const int buf = kt % 3;
        __syncthreads();            // kt,kt+1 staged; reads of buf (kt+2)%3 done
        int pf = kt + 2;
        if (pf <= ktlast)
            stage_tiles(qkv, vt, base, bh, h, w, srow8, schunk, pf, Ks[pf % 3], Vs[pf % 3]);

        // S^T = K·Q^T; kf shared across halves
        f32x4 st0[4] = {}, st1[4] = {};
        #pragma unroll
        for (int nt = 0; nt < 4; ++nt) {
            int n = nt * 16 + l15;      // key row in Ks
            #pragma unroll
            for (int kc = 0; kc < 2; ++kc) {
                int ch = (((kc * 4 + q4) ^ (n & 7)) * 8);
                bf16x8 kf = *(const bf16x8*)(&Ks[buf][n * 64 + ch]);
                st0[nt] = __builtin_amdgcn_mfma_f32_16x16x32_bf16(kf, qf[0][kc], st0[nt], 0, 0, 0);
                st1[nt] = __builtin_amdgcn_mfma_f32_16x16x32_bf16(kf, qf[1][kc], st1[nt], 0, 0, 0);
            }
        }

        if (kt == 2 * qt) {             // diagonal for half 0 (uniform branch)
            #pragma unroll
            for (int nt = 0; nt < 4; ++nt)
                #pragma unroll
                for (int r = 0; r < 4; ++r) {
                    int keyl = nt * 16 + q4 * 4 + r;
                    if (keyl > w * 16 + l15) st0[nt][r] = -1e30f;
                }
        }

        // P^T = 2^(S^T) packed to bf16x4 B-frags (k = q4*4+j), in registers
        bf16x4 pb0[4], pb1[4];
        #pragma unroll
        for (int nt = 0; nt < 4; ++nt)
            #pragma unroll
            for (int r = 0; r < 4; ++r) {
                pb0[nt][r] = (__bf16)__builtin_amdgcn_exp2f(st0[nt][r]);
                pb1[nt][r] = (__bf16)__builtin_amdgcn_exp2f(st1[nt][r]);
            }

        // O^T += V^T · P^T  (vf shared across halves); l += ones · P^T
        #pragma unroll
        for (int nt = 0; nt < 4; ++nt) {
            #pragma unroll
            for (int mt = 0; mt < 4; ++mt) {
                int row = mt * 16 + l15;                       // d row in Vs
                int ch = (nt * 2 + (q4 >> 1)) ^ (row & 7);
                bf16x4 vf = *(const bf16x4*)(&Vs[buf][row * 64 + ch * 8 + (q4 & 1) * 4]);
                o0[mt] = mfma16(vf, pb0[nt], o0[mt]);
                o1[mt] = mfma16(vf, pb1[nt], o1[mt]);
            }
            la0 = mfma16(ones4, pb0[nt], la0);
            la1 = mfma16(ones4, pb1[nt], la1);
        }
    }

    // ---- tail tile ktlast: half 0 fully masked; half 1 only ----------------
    {
        const int buf = ktlast % 3;
        __syncthreads();

        f32x4 st1[4] = {};
        #pragma unroll
        for (int nt = 0; nt < 4; ++nt) {
            int n = nt * 16 + l15;
            #pragma unroll
            for (int kc = 0; kc < 2; ++kc) {
                int ch = (((kc * 4 + q4) ^ (n & 7)) * 8);
                bf16x8 kf = *(const bf16x8*)(&Ks[buf][n * 64 + ch]);
                st1[nt] = __builtin_amdgcn_mfma_f32_16x16x32_bf16(kf, qf[1][kc], st1[nt], 0, 0, 0);
            }
        }
        bf16x4 pb1[4];
        #pragma unroll
        for (int nt = 0; nt < 4; ++nt)
            #pragma unroll
            for (int r = 0; r < 4; ++r) {
                int keyl = nt * 16 + q4 * 4 + r;
                float s = (keyl > w * 16 + l15) ? -1e30f : st1[nt][r];
                pb1[nt][r] = (__bf16)__builtin_amdgcn_exp2f(s);
            }
        #pragma unroll
        for (int nt = 0; nt < 4; ++nt) {
            #pragma unroll
            for (int mt = 0; mt < 4; ++mt) {
                int row = mt * 16 + l15;
                int ch = (nt * 2 + (q4 >> 1)) ^ (row & 7);
                bf16x4 vf = *(const bf16x4*)(&Vs[buf][row * 64 + ch * 8 + (q4 & 1) * 4]);
                o1[mt] = mfma16(vf, pb1[nt], o1[mt]);
            }
            la1 = mfma16(ones4, pb1[nt], la1);
        }
    }

    // epilogue: lane holds O^T[d = mt*16+q4*4+r][q=l15]; packed 8B stores
    float inv0 = 1.0f / la0[0], inv1 = 1.0f / la1[0];
    int row0 = qt * 128 + w * 16 + l15;
    int row1 = row0 + 64;
    #pragma unroll
    for (int mt = 0; mt < 4; ++mt) {
        union { __bf16 b[4]; ushort4 v; } p0, p1;
        #pragma unroll
        for (int r = 0; r < 4; ++r) {
            p0.b[r] = (__bf16)(o0[mt][r] * inv0);
            p1.b[r] = (__bf16)(o1[mt][r] * inv1);
        }
        int col = h * HDIM + mt * 16 + q4 * 4;
        *(ushort4*)(&outb[(base + row0) * (size_t)DMODEL + col]) = p0.v;
        *(ushort4*)(&outb[(base + row1) * (size_t)DMODEL + col]) = p1.v;
    }
}

// block = (bx, bh): processes Q-tiles qt = NT-1-bx and qt = bx (34 K-iters
// total for every block -> perfect load balance). gridDim.x = NT/2 = 8.
__global__ __launch_bounds__(256, 3) void attn_kernel(
    const u16* __restrict__ qkv, const u16* __restrict__ vt, u16* __restrict__ out)
{
    __shared__ __attribute__((aligned(16))) u16 Ks[3][64 * 64];
    __shared__ __attribute__((aligned(16))) u16 Vs[3][64 * 64];

    const int tid = threadIdx.x;
    const int w = tid >> 6, lane = tid & 63;
    const int bh = blockIdx.y;
    const int b = bh >> 4, h = bh & 15;
    const size_t base = (size_t)b * S_LEN;
    const int NT = (int)gridDim.x * 2;           // 16

    attn_pass(NT - 1 - (int)blockIdx.x, qkv, vt, (__bf16*)out, Ks, Vs, w, lane, bh, h, base);
    attn_pass((int)blockIdx.x,          qkv, vt, (__bf16*)out, Ks, Vs, w, lane, bh, h, base);
}

extern "C" void kernel_launch(void* const* d_in, const int* in_sizes, int n_in,
                              void* d_out, int out_size, void* d_ws, size_t ws_size,
                              hipStream_t stream) {
    const float* x      = (const float*)d_in[0];
    // d_in[1] = mask (causal tril) — implemented structurally, not read
    const float* w_attn = (const float*)d_in[2];
    const float* b_attn = (const float*)d_in[3];
    const float* w_proj = (const float*)d_in[4];
    const float* b_proj = (const float*)d_in[5];

    u16* xb   = (u16*)d_ws;                                   // 8192x1024 (dead after QKV GEMM)
    u16* wat  = xb  + (size_t)MTOT * DMODEL;                  // 3072x1024
    u16* wpt  = wat + (size_t)NQKV * DMODEL;                  // 1024x1024
    u16* qkv  = wpt + (size_t)DMODEL * DMODEL;                // 8192x3072
    u16* attn = qkv + (size_t)MTOT * NQKV;                    // 8192x1024
    u16* vt   = xb;                                           // Vt[64 bh][64 d][2048 s] aliases xb

    convert_x_kernel<<<(MTOT * DMODEL / 4 + 255) / 256, 256, 0, stream>>>(
        (const float4*)x, (ushort4*)xb, MTOT * DMODEL / 4);
    transpose_bf16_kernel<<<dim3(NQKV / 64, DMODEL / 64), 256, 0, stream>>>(w_attn, wat, DMODEL, NQKV);
    transpose_bf16_kernel<<<dim3(DMODEL / 64, DMODEL / 64), 256, 0, stream>>>(w_proj, wpt, DMODEL, DMODEL);

    gemm16q<4, true><<<dim3((MTOT / 256) * (NQKV / 256)), 512, 0, stream>>>(
        xb, wat, b_attn, (void*)qkv, MTOT, NQKV, DMODEL);

    transpose_v_kernel<<<dim3(S_LEN / 64, 4 * NHEAD), 256, 0, stream>>>(qkv, vt);

    attn_kernel<<<dim3(S_LEN / 256, 4 * NHEAD), 256, 0, stream>>>(qkv, vt, attn);

    gemm16q<2, false><<<dim3((MTOT / 256) * (DMODEL / 128)), 512, 0, stream>>>(
        attn, wpt, b_proj, d_out, MTOT, DMODEL, DMODEL);
}